// Round 1
// baseline (1044.946 us; speedup 1.0000x reference)
//
#include <hip/hip_runtime.h>

typedef unsigned short u16;

// ws layout (float offsets unless noted)
#define OFF_W2T   0          // [8][128][128]  w2t[d][h][k] = w2[d][k][h]
#define OFF_W3T   131072     // [8][128][64]   w3t[d][h][o] = w3[d][o][h]
#define OFF_WQT   196608     // [4][64][64]    WqT[tag][j][e] = Win_tag[e][j]
#define OFF_WKT   212992     // [4][64][64]    WkT[tag][j][e] = Win_tag[64+e][j]
#define OFF_U     229376     // [4][4][64]     folded value vectors
#define OFF_CV    230400     // [4][4]
#define OFF_CONST 230416     // 1
#define OFF_TOK_BYTES (230432 * 4)   // bf16 tokens [B][8][64]

static __device__ __forceinline__ u16 f2bf(float f) {
  unsigned int bits = __float_as_uint(f);
  bits += 0x7fffu + ((bits >> 16) & 1u);
  return (u16)(bits >> 16);
}
static __device__ __forceinline__ float bf2f(u16 u) {
  return __uint_as_float(((unsigned int)u) << 16);
}

// ---------------------------------------------------------------- prep 1
__global__ __launch_bounds__(256) void prep_transpose(
    const float* __restrict__ w2, const float* __restrict__ w3,
    const float* __restrict__ win_sa, const float* __restrict__ win_sb,
    const float* __restrict__ win_ca, const float* __restrict__ win_cb,
    float* __restrict__ ws) {
  int idx = blockIdx.x * 256 + threadIdx.x;
  if (idx < 131072) {                       // w2t[d][h][k] = w2[d][k][h]
    int d = idx >> 14, rem = idx & 16383, h = rem >> 7, k = rem & 127;
    ws[OFF_W2T + idx] = w2[(d << 14) + (k << 7) + h];
  } else if (idx < 196608) {                // w3t[d][h][o] = w3[d][o][h]
    int i = idx - 131072;
    int d = i >> 13, rem = i & 8191, h = rem >> 6, o = rem & 63;
    ws[OFF_W3T + i] = w3[(d << 13) + (o << 7) + h];
  } else {                                  // WqT / WkT
    int i = idx - 196608;                   // 32768 total
    int tag = i >> 13, rem = i & 8191, qk = rem >> 12, r2 = rem & 4095;
    int j = r2 >> 6, e = r2 & 63;
    const float* win = tag == 0 ? win_sa : tag == 1 ? win_sb : tag == 2 ? win_ca : win_cb;
    float val = win[(qk * 64 + e) * 64 + j];
    ws[(qk == 0 ? OFF_WQT : OFF_WKT) + tag * 4096 + j * 64 + e] = val;
  }
}

// ---------------------------------------------------------------- prep 2
// Fold Wo/Wf/Wv/biases:  v = Wo^T Wf_half ; u[h] = Wv[h-slice]^T v[h-slice]
__global__ __launch_bounds__(64) void prep_fold(
    const float* __restrict__ win_sa, const float* __restrict__ bin_sa,
    const float* __restrict__ wo_sa,  const float* __restrict__ bo_sa,
    const float* __restrict__ win_sb, const float* __restrict__ bin_sb,
    const float* __restrict__ wo_sb,  const float* __restrict__ bo_sb,
    const float* __restrict__ win_ca, const float* __restrict__ bin_ca,
    const float* __restrict__ wo_ca,  const float* __restrict__ bo_ca,
    const float* __restrict__ win_cb, const float* __restrict__ bin_cb,
    const float* __restrict__ wo_cb,  const float* __restrict__ bo_cb,
    const float* __restrict__ Wf, const float* __restrict__ bf,
    float* __restrict__ ws) {
  __shared__ float v_lds[64];
  const int t = threadIdx.x;  // 0..63
  const float* wins[4] = {win_sa, win_sb, win_ca, win_cb};
  const float* bins[4] = {bin_sa, bin_sb, bin_ca, bin_cb};
  const float* wos[4]  = {wo_sa, wo_sb, wo_ca, wo_cb};
  const float* bos[4]  = {bo_sa, bo_sb, bo_ca, bo_cb};
  float csum = 0.f;
  for (int tag = 0; tag < 4; tag++) {
    // tags 0(sa),2(ca) feed A_pool -> Wf[0:64]; 1(sb),3(cb) feed B_pool -> Wf[64:128]
    const float* wfh = Wf + ((tag == 0 || tag == 2) ? 0 : 64);
    float v = 0.f;
    for (int e = 0; e < 64; e++) v += wos[tag][e * 64 + t] * wfh[e];
    v_lds[t] = v;
    __syncthreads();
    for (int h = 0; h < 4; h++) {
      float u = 0.f;
      for (int dp = 0; dp < 16; dp++)
        u += wins[tag][(128 + h * 16 + dp) * 64 + t] * v_lds[h * 16 + dp];
      ws[OFF_U + tag * 256 + h * 64 + t] = u;
    }
    if (t < 4) {
      float cv = 0.f;
      for (int dp = 0; dp < 16; dp++)
        cv += bins[tag][128 + t * 16 + dp] * v_lds[t * 16 + dp];
      ws[OFF_CV + tag * 4 + t] = cv;
    }
    if (t == 0) {
      float c = 0.f;
      for (int e = 0; e < 64; e++) c += bos[tag][e] * wfh[e];
      csum += c;
    }
    __syncthreads();
  }
  if (t == 0) ws[OFF_CONST] = 0.5f * csum + bf[0];
}

// ---------------------------------------------------------------- tokens
// block = 256 threads, 64 batch rows; loop d=0..7: h1 -> h2 -> tokens(bf16)
__global__ __launch_bounds__(256) void tokens_kernel(
    const float* __restrict__ x, const float* __restrict__ w1,
    const float* __restrict__ b1, const float* __restrict__ b2,
    const float* __restrict__ b3, const float* __restrict__ ws,
    u16* __restrict__ tok_out) {
  __shared__ float xs[64][9];
  __shared__ float h1s[64][129];
  __shared__ float h2s[64][129];
  const int t = threadIdx.x;
  const int b0 = blockIdx.x * 64;
  for (int i = t; i < 512; i += 256) xs[i >> 3][i & 7] = x[b0 * 8 + i];
  __syncthreads();
  const float* w2t = ws + OFF_W2T;
  const float* w3t = ws + OFF_W3T;
  const int row4 = (t >> 4) * 4;   // phase B/C: 4 rows per thread
  const int kc = t & 15;           // phase B: k = kc*8..+7 ; phase C: o = kc*4..+3
  for (int d = 0; d < 8; d++) {
    {  // phase A: h1[row][h] = sin(x[row][d]*w1[d][h] + b1[d][h])
      int row = t & 63, hc = t >> 6;
      float xv = xs[row][d];
      const float* w1p = w1 + d * 128 + hc * 32;
      const float* b1p = b1 + d * 128 + hc * 32;
      float* h1p = &h1s[row][hc * 32];
#pragma unroll 8
      for (int j = 0; j < 32; j++) h1p[j] = __sinf(xv * w1p[j] + b1p[j]);
    }
    __syncthreads();
    {  // phase B: h2[row][k] = sin(sum_h h1[row][h]*w2t[d][h][k] + b2[d][k])
      float acc[4][8];
#pragma unroll
      for (int i = 0; i < 4; i++)
#pragma unroll
        for (int jj = 0; jj < 8; jj++) acc[i][jj] = 0.f;
      const float* wrow = w2t + (d << 14) + kc * 8;
      for (int h = 0; h < 128; h++) {
        float4 bv0 = *(const float4*)(wrow + h * 128);
        float4 bv1 = *(const float4*)(wrow + h * 128 + 4);
        float bb[8] = {bv0.x, bv0.y, bv0.z, bv0.w, bv1.x, bv1.y, bv1.z, bv1.w};
        float aa[4] = {h1s[row4 + 0][h], h1s[row4 + 1][h], h1s[row4 + 2][h], h1s[row4 + 3][h]};
#pragma unroll
        for (int i = 0; i < 4; i++)
#pragma unroll
          for (int jj = 0; jj < 8; jj++) acc[i][jj] += aa[i] * bb[jj];
      }
      const float* b2p = b2 + d * 128 + kc * 8;
#pragma unroll
      for (int i = 0; i < 4; i++)
#pragma unroll
        for (int jj = 0; jj < 8; jj++)
          h2s[row4 + i][kc * 8 + jj] = __sinf(acc[i][jj] + b2p[jj]);
    }
    __syncthreads();
    {  // phase C: tok[row][o] = sum_h h2[row][h]*w3t[d][h][o] + b3[d][o]
      float acc[4][4];
#pragma unroll
      for (int i = 0; i < 4; i++)
#pragma unroll
        for (int jj = 0; jj < 4; jj++) acc[i][jj] = 0.f;
      const float* wrow = w3t + (d << 13) + kc * 4;
      for (int h = 0; h < 128; h++) {
        float4 bv = *(const float4*)(wrow + h * 64);
        float aa[4] = {h2s[row4 + 0][h], h2s[row4 + 1][h], h2s[row4 + 2][h], h2s[row4 + 3][h]};
#pragma unroll
        for (int i = 0; i < 4; i++) {
          acc[i][0] += aa[i] * bv.x;
          acc[i][1] += aa[i] * bv.y;
          acc[i][2] += aa[i] * bv.z;
          acc[i][3] += aa[i] * bv.w;
        }
      }
      const float* b3p = b3 + d * 64 + kc * 4;
#pragma unroll
      for (int i = 0; i < 4; i++) {
        ushort4 pk;
        pk.x = f2bf(acc[i][0] + b3p[0]);
        pk.y = f2bf(acc[i][1] + b3p[1]);
        pk.z = f2bf(acc[i][2] + b3p[2]);
        pk.w = f2bf(acc[i][3] + b3p[3]);
        *(ushort4*)(tok_out + ((size_t)(b0 + row4 + i) * 8 + d) * 64 + kc * 4) = pk;
      }
    }
    __syncthreads();
  }
}

// ---------------------------------------------------------------- attention
// block = 256 (4 waves), 8 batch elements (2 per wave).
// per tag: project q,k (lane = out-dim, both elements), sv via folded u,
// then 16 lanes/element do scores+softmax+mix; shuffle-reduce.
__global__ __launch_bounds__(256) void attn_kernel(
    const float* __restrict__ ws, const u16* __restrict__ tok,
    const float* __restrict__ bin_sa, const float* __restrict__ bin_sb,
    const float* __restrict__ bin_ca, const float* __restrict__ bin_cb,
    float* __restrict__ out) {
  __shared__ float toks[8][8][64];
  __shared__ float u_lds[1024];
  __shared__ float cv_lds[16];
  __shared__ float qh_lds[8][4][64];
  __shared__ float kh_lds[8][4][64];
  __shared__ float sv_lds[8][4][4];
  __shared__ float const_lds;
  const int t = threadIdx.x;
  const int b0 = blockIdx.x * 8;
  for (int i = t; i < 4096; i += 256)
    ((float*)toks)[i] = bf2f(tok[(size_t)b0 * 512 + i]);
  for (int i = t; i < 1024; i += 256) u_lds[i] = ws[OFF_U + i];
  if (t < 16) cv_lds[t] = ws[OFF_CV + t];
  if (t == 0) const_lds = ws[OFF_CONST];
  __syncthreads();
  const int wave = t >> 6, lane = t & 63;
  const int el0 = wave * 2;
  const int el = el0 + (lane >> 5);
  const int sub = lane & 31;
  const float* bins[4] = {bin_sa, bin_sb, bin_ca, bin_cb};
  float acc_out = 0.f;
  for (int tag = 0; tag < 4; tag++) {
    const int qbase = (tag & 1) ? 4 : 0;                  // sa:A sb:B ca:A cb:B
    const int kbase = (tag == 1 || tag == 2) ? 4 : 0;     // sa:A sb:B ca:B cb:A
    const float* wqt = ws + OFF_WQT + tag * 4096;
    const float* wkt = ws + OFF_WKT + tag * 4096;
    float aq[2][4] = {{0, 0, 0, 0}, {0, 0, 0, 0}};
    float ak[2][4] = {{0, 0, 0, 0}, {0, 0, 0, 0}};
    for (int j = 0; j < 64; j += 4) {
      float wq[4], wk[4];
#pragma unroll
      for (int i = 0; i < 4; i++) {
        wq[i] = wqt[(j + i) * 64 + lane];
        wk[i] = wkt[(j + i) * 64 + lane];
      }
#pragma unroll
      for (int e = 0; e < 2; e++) {
#pragma unroll
        for (int tk = 0; tk < 4; tk++) {
          float4 tq = *(const float4*)&toks[el0 + e][qbase + tk][j];
          aq[e][tk] += tq.x * wq[0] + tq.y * wq[1] + tq.z * wq[2] + tq.w * wq[3];
          float4 tv = *(const float4*)&toks[el0 + e][kbase + tk][j];
          ak[e][tk] += tv.x * wk[0] + tv.y * wk[1] + tv.z * wk[2] + tv.w * wk[3];
        }
      }
    }
    {
      float bq = bins[tag][lane], bk = bins[tag][64 + lane];
#pragma unroll
      for (int e = 0; e < 2; e++)
#pragma unroll
        for (int tk = 0; tk < 4; tk++) {
          qh_lds[el0 + e][tk][lane] = aq[e][tk] + bq;
          kh_lds[el0 + e][tk][lane] = ak[e][tk] + bk;
        }
    }
    if (sub < 16) {  // sv[k][h] = tok_kv[k].u[h] + cv[h]
      int k = sub >> 2, h = sub & 3;
      float s = cv_lds[tag * 4 + h];
      const float* uu = &u_lds[tag * 256 + h * 64];
      const float* tp = &toks[el][kbase + k][0];
      for (int j = 0; j < 64; j += 4) {
        float4 t4 = *(const float4*)(tp + j);
        float4 u4 = *(const float4*)(uu + j);
        s += t4.x * u4.x + t4.y * u4.y + t4.z * u4.z + t4.w * u4.w;
      }
      sv_lds[el][k][h] = s;
    }
    __syncthreads();
    float part = 0.f;
    if (sub < 16) {
      int h = sub >> 2, q = sub & 3;
      const float* qp = &qh_lds[el][q][h * 16];
      float4 qv0 = *(const float4*)(qp);
      float4 qv1 = *(const float4*)(qp + 4);
      float4 qv2 = *(const float4*)(qp + 8);
      float4 qv3 = *(const float4*)(qp + 12);
      float sc[4];
#pragma unroll
      for (int k = 0; k < 4; k++) {
        const float* kp = &kh_lds[el][k][h * 16];
        float4 k0 = *(const float4*)(kp);
        float4 k1 = *(const float4*)(kp + 4);
        float4 k2 = *(const float4*)(kp + 8);
        float4 k3 = *(const float4*)(kp + 12);
        float s = qv0.x * k0.x + qv0.y * k0.y + qv0.z * k0.z + qv0.w * k0.w +
                  qv1.x * k1.x + qv1.y * k1.y + qv1.z * k1.z + qv1.w * k1.w +
                  qv2.x * k2.x + qv2.y * k2.y + qv2.z * k2.z + qv2.w * k2.w +
                  qv3.x * k3.x + qv3.y * k3.y + qv3.z * k3.z + qv3.w * k3.w;
        sc[k] = s * 0.25f;  // 1/sqrt(dh=16)
      }
      float m = fmaxf(fmaxf(sc[0], sc[1]), fmaxf(sc[2], sc[3]));
      float e0 = __expf(sc[0] - m), e1 = __expf(sc[1] - m);
      float e2 = __expf(sc[2] - m), e3 = __expf(sc[3] - m);
      float inv = 1.f / (e0 + e1 + e2 + e3);
      part = (e0 * sv_lds[el][0][h] + e1 * sv_lds[el][1][h] +
              e2 * sv_lds[el][2][h] + e3 * sv_lds[el][3][h]) * inv;
    }
    part += __shfl_xor(part, 1, 32);
    part += __shfl_xor(part, 2, 32);
    part += __shfl_xor(part, 4, 32);
    part += __shfl_xor(part, 8, 32);
    part += __shfl_xor(part, 16, 32);
    acc_out += part;
    __syncthreads();
  }
  if (sub == 0) {
    float val = 0.125f * acc_out + const_lds;
    out[b0 + el] = val > 0.f ? val : 0.01f * val;
  }
}

// ---------------------------------------------------------------- launch
extern "C" void kernel_launch(void* const* d_in, const int* in_sizes, int n_in,
                              void* d_out, int out_size, void* d_ws, size_t ws_size,
                              hipStream_t stream) {
  const float* x      = (const float*)d_in[0];
  const float* w1     = (const float*)d_in[1];
  const float* b1     = (const float*)d_in[2];
  const float* w2     = (const float*)d_in[3];
  const float* b2     = (const float*)d_in[4];
  const float* w3     = (const float*)d_in[5];
  const float* b3     = (const float*)d_in[6];
  const float* win_sa = (const float*)d_in[7];
  const float* bin_sa = (const float*)d_in[8];
  const float* wo_sa  = (const float*)d_in[9];
  const float* bo_sa  = (const float*)d_in[10];
  const float* win_sb = (const float*)d_in[11];
  const float* bin_sb = (const float*)d_in[12];
  const float* wo_sb  = (const float*)d_in[13];
  const float* bo_sb  = (const float*)d_in[14];
  const float* win_ca = (const float*)d_in[15];
  const float* bin_ca = (const float*)d_in[16];
  const float* wo_ca  = (const float*)d_in[17];
  const float* bo_ca  = (const float*)d_in[18];
  const float* win_cb = (const float*)d_in[19];
  const float* bin_cb = (const float*)d_in[20];
  const float* wo_cb  = (const float*)d_in[21];
  const float* bo_cb  = (const float*)d_in[22];
  const float* Wf     = (const float*)d_in[23];
  const float* bf     = (const float*)d_in[24];
  float* ws = (float*)d_ws;
  u16* tokbuf = (u16*)((char*)d_ws + OFF_TOK_BYTES);
  float* out = (float*)d_out;

  prep_transpose<<<896, 256, 0, stream>>>(w2, w3, win_sa, win_sb, win_ca, win_cb, ws);
  prep_fold<<<1, 64, 0, stream>>>(win_sa, bin_sa, wo_sa, bo_sa,
                                  win_sb, bin_sb, wo_sb, bo_sb,
                                  win_ca, bin_ca, wo_ca, bo_ca,
                                  win_cb, bin_cb, wo_cb, bo_cb,
                                  Wf, bf, ws);
  tokens_kernel<<<65536 / 64, 256, 0, stream>>>(x, w1, b1, b2, b3, ws, tokbuf);
  attn_kernel<<<65536 / 8, 256, 0, stream>>>(ws, tokbuf, bin_sa, bin_sb, bin_ca, bin_cb, out);
}

// Round 2
// 827.393 us; speedup vs baseline: 1.2629x; 1.2629x over previous
//
#include <hip/hip_runtime.h>

typedef unsigned short u16;
typedef __attribute__((ext_vector_type(8))) short short8;
typedef __attribute__((ext_vector_type(4))) float f32x4;

// ws float-index offsets
#define OFF_WQT   0          // [4][64][64]  WqT[tag][j][e] = Win_tag[e][j]
#define OFF_WKT   16384      // [4][64][64]
#define OFF_U     32768      // [4][4][64]
#define OFF_CV    33792      // [4][4]
#define OFF_CONST 33808
// ws byte offsets (16B-aligned)
#define OFF_W2BF_B  135296   // u16 [8][128][128]  (w2 as-is: [d][n=k_out][k=h])
#define OFF_W3BF_B  397440   // u16 [8][64][128]   (w3 as-is: [d][n=o][k=h])
#define OFF_TOK_B   528512   // u16 tokens [B][8][64]

static __device__ __forceinline__ u16 f2bf(float f) {
  unsigned int bits = __float_as_uint(f);
  bits += 0x7fffu + ((bits >> 16) & 1u);
  return (u16)(bits >> 16);
}
static __device__ __forceinline__ float bf2f(u16 u) {
  return __uint_as_float(((unsigned int)u) << 16);
}

// ---------------------------------------------------------------- prep 1
// bf16-convert w2/w3 (already [n][k] layout) + transpose Win q/k for attn.
__global__ __launch_bounds__(256) void prep_convert(
    const float* __restrict__ w2, const float* __restrict__ w3,
    const float* __restrict__ win_sa, const float* __restrict__ win_sb,
    const float* __restrict__ win_ca, const float* __restrict__ win_cb,
    float* __restrict__ ws, u16* __restrict__ w2bf, u16* __restrict__ w3bf) {
  int idx = blockIdx.x * 256 + threadIdx.x;
  if (idx < 131072) {                       // 8*128*128
    w2bf[idx] = f2bf(w2[idx]);
  } else if (idx < 196608) {                // + 8*64*128
    int i = idx - 131072;
    w3bf[i] = f2bf(w3[i]);
  } else {                                  // WqT / WkT fp32 (attn kernel)
    int i = idx - 196608;                   // 32768 total
    int tag = i >> 13, rem = i & 8191, qk = rem >> 12, r2 = rem & 4095;
    int j = r2 >> 6, e = r2 & 63;
    const float* win = tag == 0 ? win_sa : tag == 1 ? win_sb : tag == 2 ? win_ca : win_cb;
    float val = win[(qk * 64 + e) * 64 + j];
    ws[(qk == 0 ? OFF_WQT : OFF_WKT) + tag * 4096 + j * 64 + e] = val;
  }
}

// ---------------------------------------------------------------- prep 2
__global__ __launch_bounds__(64) void prep_fold(
    const float* __restrict__ win_sa, const float* __restrict__ bin_sa,
    const float* __restrict__ wo_sa,  const float* __restrict__ bo_sa,
    const float* __restrict__ win_sb, const float* __restrict__ bin_sb,
    const float* __restrict__ wo_sb,  const float* __restrict__ bo_sb,
    const float* __restrict__ win_ca, const float* __restrict__ bin_ca,
    const float* __restrict__ wo_ca,  const float* __restrict__ bo_ca,
    const float* __restrict__ win_cb, const float* __restrict__ bin_cb,
    const float* __restrict__ wo_cb,  const float* __restrict__ bo_cb,
    const float* __restrict__ Wf, const float* __restrict__ bf,
    float* __restrict__ ws) {
  __shared__ float v_lds[64];
  const int t = threadIdx.x;  // 0..63
  const float* wins[4] = {win_sa, win_sb, win_ca, win_cb};
  const float* bins[4] = {bin_sa, bin_sb, bin_ca, bin_cb};
  const float* wos[4]  = {wo_sa, wo_sb, wo_ca, wo_cb};
  const float* bos[4]  = {bo_sa, bo_sb, bo_ca, bo_cb};
  float csum = 0.f;
  for (int tag = 0; tag < 4; tag++) {
    const float* wfh = Wf + ((tag == 0 || tag == 2) ? 0 : 64);
    float v = 0.f;
    for (int e = 0; e < 64; e++) v += wos[tag][e * 64 + t] * wfh[e];
    v_lds[t] = v;
    __syncthreads();
    for (int h = 0; h < 4; h++) {
      float u = 0.f;
      for (int dp = 0; dp < 16; dp++)
        u += wins[tag][(128 + h * 16 + dp) * 64 + t] * v_lds[h * 16 + dp];
      ws[OFF_U + tag * 256 + h * 64 + t] = u;
    }
    if (t < 4) {
      float cv = 0.f;
      for (int dp = 0; dp < 16; dp++)
        cv += bins[tag][128 + t * 16 + dp] * v_lds[t * 16 + dp];
      ws[OFF_CV + tag * 4 + t] = cv;
    }
    if (t == 0) {
      float c = 0.f;
      for (int e = 0; e < 64; e++) c += bos[tag][e] * wfh[e];
      csum += c;
    }
    __syncthreads();
  }
  if (t == 0) ws[OFF_CONST] = 0.5f * csum + bf[0];
}

// ---------------------------------------------------------------- tokens (MFMA)
// 4 waves/block, each wave owns a private 16-row M-tile; zero barriers.
// h1 sin'd straight into A-frags; w2/w3 B-frags streamed from L1-resident bf16.
__global__ __launch_bounds__(256) void tokens_kernel(
    const float* __restrict__ x, const float* __restrict__ w1,
    const float* __restrict__ b1, const float* __restrict__ b2,
    const float* __restrict__ b3, const u16* __restrict__ w2bf,
    const u16* __restrict__ w3bf, u16* __restrict__ tok_out) {
  __shared__ __align__(16) u16 h2s[64 * 136];   // stride 136 bf16 = 272 B (16B-aligned)
  const int t = threadIdx.x;
  const int wave = t >> 6, lane = t & 63;
  const int m15 = lane & 15, quad = lane >> 4;
  const int b0 = blockIdx.x * 64;
  const int rowa = wave * 16 + m15;       // A-frag row (local)
  const int rowc = wave * 16 + quad * 4;  // C-rows base (local)
  float xv[8];
#pragma unroll
  for (int d = 0; d < 8; d++) xv[d] = x[(size_t)(b0 + rowa) * 8 + d];

  for (int d = 0; d < 8; d++) {
    // ---- h1 -> A-frags (A[m=lane&15][k=quad*8+j]) in registers
    short8 afr[4];
#pragma unroll
    for (int ks = 0; ks < 4; ks++) {
      const float* w1p = w1 + d * 128 + ks * 32 + quad * 8;
      const float* b1p = b1 + d * 128 + ks * 32 + quad * 8;
      float4 wa = *(const float4*)w1p, wb = *(const float4*)(w1p + 4);
      float4 ba = *(const float4*)b1p, bb = *(const float4*)(b1p + 4);
      short8 a;
      a[0] = (short)f2bf(__sinf(xv[d] * wa.x + ba.x));
      a[1] = (short)f2bf(__sinf(xv[d] * wa.y + ba.y));
      a[2] = (short)f2bf(__sinf(xv[d] * wa.z + ba.z));
      a[3] = (short)f2bf(__sinf(xv[d] * wa.w + ba.w));
      a[4] = (short)f2bf(__sinf(xv[d] * wb.x + bb.x));
      a[5] = (short)f2bf(__sinf(xv[d] * wb.y + bb.y));
      a[6] = (short)f2bf(__sinf(xv[d] * wb.z + bb.z));
      a[7] = (short)f2bf(__sinf(xv[d] * wb.w + bb.w));
      afr[ks] = a;
    }
    // ---- layer2: [16,128] @ [128,128] -> 8 N-tiles
    f32x4 acc2[8];
#pragma unroll
    for (int nt = 0; nt < 8; nt++) acc2[nt] = (f32x4){0.f, 0.f, 0.f, 0.f};
#pragma unroll
    for (int ks = 0; ks < 4; ks++) {
      const u16* bp = w2bf + d * 16384 + m15 * 128 + ks * 32 + quad * 8;
#pragma unroll
      for (int nt = 0; nt < 8; nt++) {
        short8 bfr = *(const short8*)(bp + nt * 2048);
        acc2[nt] = __builtin_amdgcn_mfma_f32_16x16x32_bf16(afr[ks], bfr, acc2[nt], 0, 0, 0);
      }
    }
    // ---- ep2: sin -> bf16 -> wave-private LDS rows (C: col=lane&15, row=quad*4+r)
#pragma unroll
    for (int nt = 0; nt < 8; nt++) {
      float bias = b2[d * 128 + m15 + 16 * nt];
#pragma unroll
      for (int r = 0; r < 4; r++)
        h2s[(rowc + r) * 136 + m15 + 16 * nt] = f2bf(__sinf(acc2[nt][r] + bias));
    }
    // ---- layer3: [16,128] @ [128,64] -> 4 N-tiles
    f32x4 acc3[4];
#pragma unroll
    for (int nt = 0; nt < 4; nt++) acc3[nt] = (f32x4){0.f, 0.f, 0.f, 0.f};
#pragma unroll
    for (int ks = 0; ks < 4; ks++) {
      short8 af = *(const short8*)(h2s + (wave * 16 + m15) * 136 + ks * 32 + quad * 8);
      const u16* bp3 = w3bf + d * 8192 + m15 * 128 + ks * 32 + quad * 8;
#pragma unroll
      for (int nt = 0; nt < 4; nt++) {
        short8 bfr = *(const short8*)(bp3 + nt * 2048);
        acc3[nt] = __builtin_amdgcn_mfma_f32_16x16x32_bf16(af, bfr, acc3[nt], 0, 0, 0);
      }
    }
    // ---- ep3: +b3 -> bf16 tokens (global)
#pragma unroll
    for (int nt = 0; nt < 4; nt++) {
      float bias = b3[d * 64 + m15 + 16 * nt];
#pragma unroll
      for (int r = 0; r < 4; r++)
        tok_out[((size_t)(b0 + rowc + r) * 8 + d) * 64 + m15 + 16 * nt] =
            f2bf(acc3[nt][r] + bias);
    }
  }
}

// ---------------------------------------------------------------- attention (unchanged R1)
__global__ __launch_bounds__(256) void attn_kernel(
    const float* __restrict__ ws, const u16* __restrict__ tok,
    const float* __restrict__ bin_sa, const float* __restrict__ bin_sb,
    const float* __restrict__ bin_ca, const float* __restrict__ bin_cb,
    float* __restrict__ out) {
  __shared__ float toks[8][8][64];
  __shared__ float u_lds[1024];
  __shared__ float cv_lds[16];
  __shared__ float qh_lds[8][4][64];
  __shared__ float kh_lds[8][4][64];
  __shared__ float sv_lds[8][4][4];
  __shared__ float const_lds;
  const int t = threadIdx.x;
  const int b0 = blockIdx.x * 8;
  for (int i = t; i < 4096; i += 256)
    ((float*)toks)[i] = bf2f(tok[(size_t)b0 * 512 + i]);
  for (int i = t; i < 1024; i += 256) u_lds[i] = ws[OFF_U + i];
  if (t < 16) cv_lds[t] = ws[OFF_CV + t];
  if (t == 0) const_lds = ws[OFF_CONST];
  __syncthreads();
  const int wave = t >> 6, lane = t & 63;
  const int el0 = wave * 2;
  const int el = el0 + (lane >> 5);
  const int sub = lane & 31;
  const float* bins[4] = {bin_sa, bin_sb, bin_ca, bin_cb};
  float acc_out = 0.f;
  for (int tag = 0; tag < 4; tag++) {
    const int qbase = (tag & 1) ? 4 : 0;
    const int kbase = (tag == 1 || tag == 2) ? 4 : 0;
    const float* wqt = ws + OFF_WQT + tag * 4096;
    const float* wkt = ws + OFF_WKT + tag * 4096;
    float aq[2][4] = {{0, 0, 0, 0}, {0, 0, 0, 0}};
    float ak[2][4] = {{0, 0, 0, 0}, {0, 0, 0, 0}};
    for (int j = 0; j < 64; j += 4) {
      float wq[4], wk[4];
#pragma unroll
      for (int i = 0; i < 4; i++) {
        wq[i] = wqt[(j + i) * 64 + lane];
        wk[i] = wkt[(j + i) * 64 + lane];
      }
#pragma unroll
      for (int e = 0; e < 2; e++) {
#pragma unroll
        for (int tk = 0; tk < 4; tk++) {
          float4 tq = *(const float4*)&toks[el0 + e][qbase + tk][j];
          aq[e][tk] += tq.x * wq[0] + tq.y * wq[1] + tq.z * wq[2] + tq.w * wq[3];
          float4 tv = *(const float4*)&toks[el0 + e][kbase + tk][j];
          ak[e][tk] += tv.x * wk[0] + tv.y * wk[1] + tv.z * wk[2] + tv.w * wk[3];
        }
      }
    }
    {
      float bq = bins[tag][lane], bk = bins[tag][64 + lane];
#pragma unroll
      for (int e = 0; e < 2; e++)
#pragma unroll
        for (int tk = 0; tk < 4; tk++) {
          qh_lds[el0 + e][tk][lane] = aq[e][tk] + bq;
          kh_lds[el0 + e][tk][lane] = ak[e][tk] + bk;
        }
    }
    if (sub < 16) {
      int k = sub >> 2, h = sub & 3;
      float s = cv_lds[tag * 4 + h];
      const float* uu = &u_lds[tag * 256 + h * 64];
      const float* tp = &toks[el][kbase + k][0];
      for (int j = 0; j < 64; j += 4) {
        float4 t4 = *(const float4*)(tp + j);
        float4 u4 = *(const float4*)(uu + j);
        s += t4.x * u4.x + t4.y * u4.y + t4.z * u4.z + t4.w * u4.w;
      }
      sv_lds[el][k][h] = s;
    }
    __syncthreads();
    float part = 0.f;
    if (sub < 16) {
      int h = sub >> 2, q = sub & 3;
      const float* qp = &qh_lds[el][q][h * 16];
      float4 qv0 = *(const float4*)(qp);
      float4 qv1 = *(const float4*)(qp + 4);
      float4 qv2 = *(const float4*)(qp + 8);
      float4 qv3 = *(const float4*)(qp + 12);
      float sc[4];
#pragma unroll
      for (int k = 0; k < 4; k++) {
        const float* kp = &kh_lds[el][k][h * 16];
        float4 k0 = *(const float4*)(kp);
        float4 k1 = *(const float4*)(kp + 4);
        float4 k2 = *(const float4*)(kp + 8);
        float4 k3 = *(const float4*)(kp + 12);
        float s = qv0.x * k0.x + qv0.y * k0.y + qv0.z * k0.z + qv0.w * k0.w +
                  qv1.x * k1.x + qv1.y * k1.y + qv1.z * k1.z + qv1.w * k1.w +
                  qv2.x * k2.x + qv2.y * k2.y + qv2.z * k2.z + qv2.w * k2.w +
                  qv3.x * k3.x + qv3.y * k3.y + qv3.z * k3.z + qv3.w * k3.w;
        sc[k] = s * 0.25f;
      }
      float m = fmaxf(fmaxf(sc[0], sc[1]), fmaxf(sc[2], sc[3]));
      float e0 = __expf(sc[0] - m), e1 = __expf(sc[1] - m);
      float e2 = __expf(sc[2] - m), e3 = __expf(sc[3] - m);
      float inv = 1.f / (e0 + e1 + e2 + e3);
      part = (e0 * sv_lds[el][0][h] + e1 * sv_lds[el][1][h] +
              e2 * sv_lds[el][2][h] + e3 * sv_lds[el][3][h]) * inv;
    }
    part += __shfl_xor(part, 1, 32);
    part += __shfl_xor(part, 2, 32);
    part += __shfl_xor(part, 4, 32);
    part += __shfl_xor(part, 8, 32);
    part += __shfl_xor(part, 16, 32);
    acc_out += part;
    __syncthreads();
  }
  if (sub == 0) {
    float val = 0.125f * acc_out + const_lds;
    out[b0 + el] = val > 0.f ? val : 0.01f * val;
  }
}

// ---------------------------------------------------------------- launch
extern "C" void kernel_launch(void* const* d_in, const int* in_sizes, int n_in,
                              void* d_out, int out_size, void* d_ws, size_t ws_size,
                              hipStream_t stream) {
  const float* x      = (const float*)d_in[0];
  const float* w1     = (const float*)d_in[1];
  const float* b1     = (const float*)d_in[2];
  const float* w2     = (const float*)d_in[3];
  const float* b2     = (const float*)d_in[4];
  const float* w3     = (const float*)d_in[5];
  const float* b3     = (const float*)d_in[6];
  const float* win_sa = (const float*)d_in[7];
  const float* bin_sa = (const float*)d_in[8];
  const float* wo_sa  = (const float*)d_in[9];
  const float* bo_sa  = (const float*)d_in[10];
  const float* win_sb = (const float*)d_in[11];
  const float* bin_sb = (const float*)d_in[12];
  const float* wo_sb  = (const float*)d_in[13];
  const float* bo_sb  = (const float*)d_in[14];
  const float* win_ca = (const float*)d_in[15];
  const float* bin_ca = (const float*)d_in[16];
  const float* wo_ca  = (const float*)d_in[17];
  const float* bo_ca  = (const float*)d_in[18];
  const float* win_cb = (const float*)d_in[19];
  const float* bin_cb = (const float*)d_in[20];
  const float* wo_cb  = (const float*)d_in[21];
  const float* bo_cb  = (const float*)d_in[22];
  const float* Wf     = (const float*)d_in[23];
  const float* bf     = (const float*)d_in[24];
  float* ws = (float*)d_ws;
  u16* w2bf  = (u16*)((char*)d_ws + OFF_W2BF_B);
  u16* w3bf  = (u16*)((char*)d_ws + OFF_W3BF_B);
  u16* tokbuf = (u16*)((char*)d_ws + OFF_TOK_B);
  float* out = (float*)d_out;

  prep_convert<<<896, 256, 0, stream>>>(w2, w3, win_sa, win_sb, win_ca, win_cb,
                                        ws, w2bf, w3bf);
  prep_fold<<<1, 64, 0, stream>>>(win_sa, bin_sa, wo_sa, bo_sa,
                                  win_sb, bin_sb, wo_sb, bo_sb,
                                  win_ca, bin_ca, wo_ca, bo_ca,
                                  win_cb, bin_cb, wo_cb, bo_cb,
                                  Wf, bf, ws);
  tokens_kernel<<<65536 / 64, 256, 0, stream>>>(x, w1, b1, b2, b3, w2bf, w3bf, tokbuf);
  attn_kernel<<<65536 / 8, 256, 0, stream>>>(ws, tokbuf, bin_sa, bin_sb, bin_ca, bin_cb, out);
}

// Round 4
// 484.631 us; speedup vs baseline: 2.1562x; 1.7073x over previous
//
#include <hip/hip_runtime.h>

typedef unsigned short u16;
typedef __attribute__((ext_vector_type(8))) short short8;
typedef __attribute__((ext_vector_type(4))) float f32x4;

// ws float-index offsets
#define OFF_U     0       // [4][4][64] folded value vectors (tag,h,k)
#define OFF_CV    1024    // [4][4]
#define OFF_CONST 1040
#define OFF_BA    1056    // [272] fp32 bias for WA cols
#define OFF_BB    1328    // [272]
// ws byte offsets (16B-aligned)
#define OFF_WA_B    6400     // u16 [272][64]
#define OFF_WB_B    41216    // u16 [272][64]
#define OFF_W2BF_B  76032    // u16 [8][128][128]
#define OFF_W3BF_B  338176   // u16 [8][64][128]
#define OFF_TOK_B   469248   // u16 tokens [B][8][64]

#define P_STRIDE 280
#define PSIDE    (32 * P_STRIDE)
#define TOKL_STRIDE 520

static __device__ __forceinline__ u16 f2bf(float f) {
  unsigned int bits = __float_as_uint(f);
  bits += 0x7fffu + ((bits >> 16) & 1u);
  return (u16)(bits >> 16);
}
static __device__ __forceinline__ float bf2f(u16 u) {
  return __uint_as_float(((unsigned int)u) << 16);
}
static __device__ __forceinline__ void ld16(const u16* p, float* o) {
  short8 v0 = *(const short8*)p;
  short8 v1 = *(const short8*)(p + 8);
#pragma unroll
  for (int i = 0; i < 8; i++) {
    o[i] = bf2f((u16)v0[i]);
    o[8 + i] = bf2f((u16)v1[i]);
  }
}

// ---------------------------------------------------------------- prep 1: fold
__global__ __launch_bounds__(64) void prep_fold(
    const float* __restrict__ win_sa, const float* __restrict__ bin_sa,
    const float* __restrict__ wo_sa,  const float* __restrict__ bo_sa,
    const float* __restrict__ win_sb, const float* __restrict__ bin_sb,
    const float* __restrict__ wo_sb,  const float* __restrict__ bo_sb,
    const float* __restrict__ win_ca, const float* __restrict__ bin_ca,
    const float* __restrict__ wo_ca,  const float* __restrict__ bo_ca,
    const float* __restrict__ win_cb, const float* __restrict__ bin_cb,
    const float* __restrict__ wo_cb,  const float* __restrict__ bo_cb,
    const float* __restrict__ Wf, const float* __restrict__ bf,
    float* __restrict__ ws) {
  __shared__ float v_lds[64];
  const int t = threadIdx.x;  // 0..63
  const float* wins[4] = {win_sa, win_sb, win_ca, win_cb};
  const float* bins[4] = {bin_sa, bin_sb, bin_ca, bin_cb};
  const float* wos[4]  = {wo_sa, wo_sb, wo_ca, wo_cb};
  const float* bos[4]  = {bo_sa, bo_sb, bo_ca, bo_cb};
  float csum = 0.f;
  for (int tag = 0; tag < 4; tag++) {
    const float* wfh = Wf + ((tag == 0 || tag == 2) ? 0 : 64);
    float v = 0.f;
    for (int e = 0; e < 64; e++) v += wos[tag][e * 64 + t] * wfh[e];
    v_lds[t] = v;
    __syncthreads();
    for (int h = 0; h < 4; h++) {
      float u = 0.f;
      for (int dp = 0; dp < 16; dp++)
        u += wins[tag][(128 + h * 16 + dp) * 64 + t] * v_lds[h * 16 + dp];
      ws[OFF_U + tag * 256 + h * 64 + t] = u;
    }
    if (t < 4) {
      float cv = 0.f;
      for (int dp = 0; dp < 16; dp++)
        cv += bins[tag][128 + t * 16 + dp] * v_lds[t * 16 + dp];
      ws[OFF_CV + tag * 4 + t] = cv;
    }
    if (t == 0) {
      float c = 0.f;
      for (int e = 0; e < 64; e++) c += bos[tag][e] * wfh[e];
      csum += c;
    }
    __syncthreads();
  }
  if (t == 0) ws[OFF_CONST] = 0.5f * csum + bf[0];
}

// ---------------------------------------------------------------- prep 2: pack
// w2/w3 -> bf16 ; WA/WB packed projection matrices (q scaled 0.25) ; bA/bB.
__global__ __launch_bounds__(256) void prep_pack(
    const float* __restrict__ w2, const float* __restrict__ w3,
    const float* __restrict__ win_sa, const float* __restrict__ win_sb,
    const float* __restrict__ win_ca, const float* __restrict__ win_cb,
    const float* __restrict__ bin_sa, const float* __restrict__ bin_sb,
    const float* __restrict__ bin_ca, const float* __restrict__ bin_cb,
    float* __restrict__ ws, u16* __restrict__ w2bf, u16* __restrict__ w3bf,
    u16* __restrict__ WA, u16* __restrict__ WB) {
  int idx = blockIdx.x * 256 + threadIdx.x;
  if (idx < 131072) {
    w2bf[idx] = f2bf(w2[idx]);
  } else if (idx < 196608) {
    int i = idx - 131072;
    w3bf[i] = f2bf(w3[i]);
  } else if (idx < 214016) {        // WA [272][64]
    int i = idx - 196608, n = i >> 6, k = i & 63;
    float v;
    if (n < 64)       v = win_sa[n * 64 + k] * 0.25f;          // q_sa
    else if (n < 128) v = win_sa[n * 64 + k];                  // k_sa
    else if (n < 192) v = win_ca[(n - 128) * 64 + k] * 0.25f;  // q_ca
    else if (n < 256) v = win_cb[(n - 128) * 64 + k];          // k_cb (rows 64:128)
    else if (n < 260) v = ws[OFF_U + 0 * 256 + (n - 256) * 64 + k];  // u_sa
    else if (n < 264) v = ws[OFF_U + 3 * 256 + (n - 260) * 64 + k];  // u_cb
    else              v = 0.f;
    WA[i] = f2bf(v);
  } else if (idx < 231424) {        // WB [272][64]
    int i = idx - 214016, n = i >> 6, k = i & 63;
    float v;
    if (n < 64)       v = win_sb[n * 64 + k] * 0.25f;          // q_sb
    else if (n < 128) v = win_sb[n * 64 + k];                  // k_sb
    else if (n < 192) v = win_cb[(n - 128) * 64 + k] * 0.25f;  // q_cb
    else if (n < 256) v = win_ca[(n - 128) * 64 + k];          // k_ca
    else if (n < 260) v = ws[OFF_U + 1 * 256 + (n - 256) * 64 + k];  // u_sb
    else if (n < 264) v = ws[OFF_U + 2 * 256 + (n - 260) * 64 + k];  // u_ca
    else              v = 0.f;
    WB[i] = f2bf(v);
  } else if (idx < 231696) {        // bA
    int n = idx - 231424;
    float v;
    if (n < 64)       v = bin_sa[n] * 0.25f;
    else if (n < 128) v = bin_sa[n];
    else if (n < 192) v = bin_ca[n - 128] * 0.25f;
    else if (n < 256) v = bin_cb[n - 128];
    else if (n < 260) v = ws[OFF_CV + 0 * 4 + (n - 256)];
    else if (n < 264) v = ws[OFF_CV + 3 * 4 + (n - 260)];
    else              v = 0.f;
    ws[OFF_BA + n] = v;
  } else if (idx < 231968) {        // bB
    int n = idx - 231696;
    float v;
    if (n < 64)       v = bin_sb[n] * 0.25f;
    else if (n < 128) v = bin_sb[n];
    else if (n < 192) v = bin_cb[n - 128] * 0.25f;
    else if (n < 256) v = bin_ca[n - 128];
    else if (n < 260) v = ws[OFF_CV + 1 * 4 + (n - 256)];
    else if (n < 264) v = ws[OFF_CV + 2 * 4 + (n - 260)];
    else              v = 0.f;
    ws[OFF_BB + n] = v;
  }
}

// ---------------------------------------------------------------- tokens (MFMA)
__global__ __launch_bounds__(256) void tokens_kernel(
    const float* __restrict__ x, const float* __restrict__ w1,
    const float* __restrict__ b1, const float* __restrict__ b2,
    const float* __restrict__ b3, const u16* __restrict__ w2bf,
    const u16* __restrict__ w3bf, u16* __restrict__ tok_out) {
  __shared__ __align__(16) u16 h2s[64 * 136];
  __shared__ __align__(16) u16 tokstage[64 * 72];
  const int t = threadIdx.x;
  const int wave = t >> 6, lane = t & 63;
  const int m15 = lane & 15, quad = lane >> 4;
  const int b0 = blockIdx.x * 64;
  const int rowa = wave * 16 + m15;
  const int rowc = wave * 16 + quad * 4;
  float xv[8];
#pragma unroll
  for (int d = 0; d < 8; d++) xv[d] = x[(size_t)(b0 + rowa) * 8 + d];

  for (int d = 0; d < 8; d++) {
    // ---- h1 -> A-frags
    short8 afr[4];
#pragma unroll
    for (int ks = 0; ks < 4; ks++) {
      const float* w1p = w1 + d * 128 + ks * 32 + quad * 8;
      const float* b1p = b1 + d * 128 + ks * 32 + quad * 8;
      float4 wa = *(const float4*)w1p, wb = *(const float4*)(w1p + 4);
      float4 ba = *(const float4*)b1p, bb = *(const float4*)(b1p + 4);
      short8 a;
      a[0] = (short)f2bf(__sinf(xv[d] * wa.x + ba.x));
      a[1] = (short)f2bf(__sinf(xv[d] * wa.y + ba.y));
      a[2] = (short)f2bf(__sinf(xv[d] * wa.z + ba.z));
      a[3] = (short)f2bf(__sinf(xv[d] * wa.w + ba.w));
      a[4] = (short)f2bf(__sinf(xv[d] * wb.x + bb.x));
      a[5] = (short)f2bf(__sinf(xv[d] * wb.y + bb.y));
      a[6] = (short)f2bf(__sinf(xv[d] * wb.z + bb.z));
      a[7] = (short)f2bf(__sinf(xv[d] * wb.w + bb.w));
      afr[ks] = a;
    }
    // ---- layer2
    f32x4 acc2[8];
#pragma unroll
    for (int nt = 0; nt < 8; nt++) acc2[nt] = (f32x4){0.f, 0.f, 0.f, 0.f};
#pragma unroll
    for (int ks = 0; ks < 4; ks++) {
      const u16* bp = w2bf + d * 16384 + m15 * 128 + ks * 32 + quad * 8;
#pragma unroll
      for (int nt = 0; nt < 8; nt++) {
        short8 bfr = *(const short8*)(bp + nt * 2048);
        acc2[nt] = __builtin_amdgcn_mfma_f32_16x16x32_bf16(afr[ks], bfr, acc2[nt], 0, 0, 0);
      }
    }
    // ---- ep2 -> h2s (bf16)
#pragma unroll
    for (int nt = 0; nt < 8; nt++) {
      float bias = b2[d * 128 + m15 + 16 * nt];
#pragma unroll
      for (int r = 0; r < 4; r++)
        h2s[(rowc + r) * 136 + m15 + 16 * nt] = f2bf(__sinf(acc2[nt][r] + bias));
    }
    // ---- layer3
    f32x4 acc3[4];
#pragma unroll
    for (int nt = 0; nt < 4; nt++) acc3[nt] = (f32x4){0.f, 0.f, 0.f, 0.f};
#pragma unroll
    for (int ks = 0; ks < 4; ks++) {
      short8 af = *(const short8*)(h2s + (wave * 16 + m15) * 136 + ks * 32 + quad * 8);
      const u16* bp3 = w3bf + d * 8192 + m15 * 128 + ks * 32 + quad * 8;
#pragma unroll
      for (int nt = 0; nt < 4; nt++) {
        short8 bfr = *(const short8*)(bp3 + nt * 2048);
        acc3[nt] = __builtin_amdgcn_mfma_f32_16x16x32_bf16(af, bfr, acc3[nt], 0, 0, 0);
      }
    }
    // ---- ep3: stage to LDS, then coalesced 16B global stores (FULL 64 cols)
#pragma unroll
    for (int nt = 0; nt < 4; nt++) {
      float bias = b3[d * 64 + m15 + 16 * nt];
#pragma unroll
      for (int r = 0; r < 4; r++)
        tokstage[(rowc + r) * 72 + m15 + 16 * nt] = f2bf(acc3[nt][r] + bias);
    }
    __syncthreads();
    {
      int row_l = wave * 16 + (lane >> 2);
#pragma unroll
      for (int it = 0; it < 2; it++) {
        int chunk = (lane & 3) + it * 4;   // 8 chunks x 8 u16 = 64 cols
        short8 v = *(const short8*)&tokstage[row_l * 72 + chunk * 8];
        *(short8*)(tok_out + ((size_t)(b0 + row_l) * 8 + d) * 64 + chunk * 8) = v;
      }
    }
    __syncthreads();
  }
}

// ---------------------------------------------------------------- attention (MFMA proj)
// block = 256 thr / 8 elems. Stage A: 4 waves x one 16-row M-tile
// (side = w>>1, mt = w&1), P[2][32][280] bf16 in LDS. Stage B: VALU softmax.
__global__ __launch_bounds__(256) void attn_kernel(
    const float* __restrict__ ws, const u16* __restrict__ tok,
    const u16* __restrict__ WA, const u16* __restrict__ WB,
    float* __restrict__ out) {
  __shared__ __align__(16) u16 tokl[8 * TOKL_STRIDE];
  __shared__ __align__(16) u16 P[2 * PSIDE];
  const int t = threadIdx.x;
  const int b0 = blockIdx.x * 8;
  {  // tokens -> LDS (padded per-elem stride)
    const short8* g = (const short8*)(tok + (size_t)b0 * 512);
#pragma unroll
    for (int it = 0; it < 2; it++) {
      int c = t + it * 256;
      short8 v = g[c];
      *(short8*)&tokl[(c >> 6) * TOKL_STRIDE + (c & 63) * 8] = v;
    }
  }
  __syncthreads();
  const int wave = t >> 6, lane = t & 63;
  const int m15 = lane & 15, quad = lane >> 4;
  {  // stage A: P = tok @ W (+bias), bf16
    const int side = wave >> 1, mt = wave & 1;
    const u16* W = side ? WB : WA;
    const float* bias = ws + (side ? OFF_BB : OFF_BA);
    const int e = mt * 4 + (m15 >> 2);
    const int d = (m15 & 3) + side * 4;
    const u16* abase = &tokl[e * TOKL_STRIDE + d * 64 + quad * 8];
    short8 a0 = *(const short8*)(abase);
    short8 a1 = *(const short8*)(abase + 32);
    u16* Pb = &P[side * PSIDE];
    const int rowc = mt * 16 + quad * 4;
    for (int nt = 0; nt < 17; nt++) {
      const u16* bp = W + (nt * 16 + m15) * 64 + quad * 8;
      short8 bf0 = *(const short8*)(bp);
      short8 bf1 = *(const short8*)(bp + 32);
      f32x4 acc = {0.f, 0.f, 0.f, 0.f};
      acc = __builtin_amdgcn_mfma_f32_16x16x32_bf16(a0, bf0, acc, 0, 0, 0);
      acc = __builtin_amdgcn_mfma_f32_16x16x32_bf16(a1, bf1, acc, 0, 0, 0);
      float bi = bias[nt * 16 + m15];
#pragma unroll
      for (int r = 0; r < 4; r++)
        Pb[(rowc + r) * P_STRIDE + m15 + 16 * nt] = f2bf(acc[r] + bi);
    }
  }
  __syncthreads();
  // stage B: softmax + folded-V mix. thread -> (elem = t>>5, tagbase, h, q)
  const float cst = ws[OFF_CONST];
  const int elem = t >> 5, sub = t & 31;
  const int tb = sub >> 4, h = (sub >> 2) & 3, q = sub & 3;
  float acc = 0.f;
#pragma unroll
  for (int ti = 0; ti < 2; ti++) {
    const int tag = tb + ti * 2;
    const int qs = tag & 1, cross = tag >> 1;
    const int ks2 = qs ^ cross;
    const u16* Pq = P + qs * PSIDE + (elem * 4 + q) * P_STRIDE + cross * 128 + h * 16;
    float qv[16];
    ld16(Pq, qv);
    const u16* Pk = P + ks2 * PSIDE + (elem * 4) * P_STRIDE + 64 + cross * 128 + h * 16;
    float sc[4];
#pragma unroll
    for (int k = 0; k < 4; k++) {
      float kv[16];
      ld16(Pk + k * P_STRIDE, kv);
      float s = 0.f;
#pragma unroll
      for (int i = 0; i < 16; i++) s += qv[i] * kv[i];
      sc[k] = s;
    }
    float mx = fmaxf(fmaxf(sc[0], sc[1]), fmaxf(sc[2], sc[3]));
    float e0 = __expf(sc[0] - mx), e1 = __expf(sc[1] - mx);
    float e2 = __expf(sc[2] - mx), e3 = __expf(sc[3] - mx);
    const u16* Psv = P + ks2 * PSIDE + (elem * 4) * P_STRIDE + 256 + cross * 4 + h;
    float o = e0 * bf2f(Psv[0]) + e1 * bf2f(Psv[P_STRIDE]) +
              e2 * bf2f(Psv[2 * P_STRIDE]) + e3 * bf2f(Psv[3 * P_STRIDE]);
    acc += o / (e0 + e1 + e2 + e3);
  }
  acc += __shfl_xor(acc, 1);
  acc += __shfl_xor(acc, 2);
  acc += __shfl_xor(acc, 4);
  acc += __shfl_xor(acc, 8);
  acc += __shfl_xor(acc, 16);
  if (sub == 0) {
    float val = 0.125f * acc + cst;
    out[b0 + elem] = val > 0.f ? val : 0.01f * val;
  }
}

// ---------------------------------------------------------------- launch
extern "C" void kernel_launch(void* const* d_in, const int* in_sizes, int n_in,
                              void* d_out, int out_size, void* d_ws, size_t ws_size,
                              hipStream_t stream) {
  const float* x      = (const float*)d_in[0];
  const float* w1     = (const float*)d_in[1];
  const float* b1     = (const float*)d_in[2];
  const float* w2     = (const float*)d_in[3];
  const float* b2     = (const float*)d_in[4];
  const float* w3     = (const float*)d_in[5];
  const float* b3     = (const float*)d_in[6];
  const float* win_sa = (const float*)d_in[7];
  const float* bin_sa = (const float*)d_in[8];
  const float* wo_sa  = (const float*)d_in[9];
  const float* bo_sa  = (const float*)d_in[10];
  const float* win_sb = (const float*)d_in[11];
  const float* bin_sb = (const float*)d_in[12];
  const float* wo_sb  = (const float*)d_in[13];
  const float* bo_sb  = (const float*)d_in[14];
  const float* win_ca = (const float*)d_in[15];
  const float* bin_ca = (const float*)d_in[16];
  const float* wo_ca  = (const float*)d_in[17];
  const float* bo_ca  = (const float*)d_in[18];
  const float* win_cb = (const float*)d_in[19];
  const float* bin_cb = (const float*)d_in[20];
  const float* wo_cb  = (const float*)d_in[21];
  const float* bo_cb  = (const float*)d_in[22];
  const float* Wf     = (const float*)d_in[23];
  const float* bf     = (const float*)d_in[24];
  float* ws = (float*)d_ws;
  u16* WAp    = (u16*)((char*)d_ws + OFF_WA_B);
  u16* WBp    = (u16*)((char*)d_ws + OFF_WB_B);
  u16* w2bf   = (u16*)((char*)d_ws + OFF_W2BF_B);
  u16* w3bf   = (u16*)((char*)d_ws + OFF_W3BF_B);
  u16* tokbuf = (u16*)((char*)d_ws + OFF_TOK_B);
  float* out = (float*)d_out;

  prep_fold<<<1, 64, 0, stream>>>(win_sa, bin_sa, wo_sa, bo_sa,
                                  win_sb, bin_sb, wo_sb, bo_sb,
                                  win_ca, bin_ca, wo_ca, bo_ca,
                                  win_cb, bin_cb, wo_cb, bo_cb,
                                  Wf, bf, ws);
  prep_pack<<<907, 256, 0, stream>>>(w2, w3, win_sa, win_sb, win_ca, win_cb,
                                     bin_sa, bin_sb, bin_ca, bin_cb,
                                     ws, w2bf, w3bf, WAp, WBp);
  tokens_kernel<<<65536 / 64, 256, 0, stream>>>(x, w1, b1, b2, b3, w2bf, w3bf, tokbuf);
  attn_kernel<<<65536 / 8, 256, 0, stream>>>(ws, tokbuf, WAp, WBp, out);
}

// Round 5
// 440.444 us; speedup vs baseline: 2.3725x; 1.1003x over previous
//
#include <hip/hip_runtime.h>

typedef unsigned short u16;
typedef __attribute__((ext_vector_type(8))) short short8;
typedef __attribute__((ext_vector_type(4))) float f32x4;

// ws float-index offsets
#define OFF_U     0       // [4][4][64] folded value vectors (tag,h,k)
#define OFF_CV    1024    // [4][4]
#define OFF_CONST 1040
#define OFF_BA    1056    // [272] fp32 bias for WA cols
#define OFF_BB    1328    // [272]
// ws byte offsets (16B-aligned)
#define OFF_WA_B    6400     // u16 [272][64]
#define OFF_WB_B    41216    // u16 [272][64]
#define OFF_W2BF_B  76032    // u16 [8][128][128]
#define OFF_W3BF_B  338176   // u16 [8][64][128]
#define OFF_TOK_B   469248   // u16 tokens [B][8][64]

#define P_STRIDE 280
#define PSIDE    (32 * P_STRIDE)
#define TOKL_STRIDE 520

static __device__ __forceinline__ u16 f2bf(float f) {
  unsigned int bits = __float_as_uint(f);
  bits += 0x7fffu + ((bits >> 16) & 1u);
  return (u16)(bits >> 16);
}
static __device__ __forceinline__ float bf2f(u16 u) {
  return __uint_as_float(((unsigned int)u) << 16);
}
static __device__ __forceinline__ void ld16(const u16* p, float* o) {
  short8 v0 = *(const short8*)p;
  short8 v1 = *(const short8*)(p + 8);
#pragma unroll
  for (int i = 0; i < 8; i++) {
    o[i] = bf2f((u16)v0[i]);
    o[8 + i] = bf2f((u16)v1[i]);
  }
}

// ---------------------------------------------------------------- prep 1: fold
__global__ __launch_bounds__(64) void prep_fold(
    const float* __restrict__ win_sa, const float* __restrict__ bin_sa,
    const float* __restrict__ wo_sa,  const float* __restrict__ bo_sa,
    const float* __restrict__ win_sb, const float* __restrict__ bin_sb,
    const float* __restrict__ wo_sb,  const float* __restrict__ bo_sb,
    const float* __restrict__ win_ca, const float* __restrict__ bin_ca,
    const float* __restrict__ wo_ca,  const float* __restrict__ bo_ca,
    const float* __restrict__ win_cb, const float* __restrict__ bin_cb,
    const float* __restrict__ wo_cb,  const float* __restrict__ bo_cb,
    const float* __restrict__ Wf, const float* __restrict__ bf,
    float* __restrict__ ws) {
  __shared__ float v_lds[64];
  const int t = threadIdx.x;  // 0..63
  const float* wins[4] = {win_sa, win_sb, win_ca, win_cb};
  const float* bins[4] = {bin_sa, bin_sb, bin_ca, bin_cb};
  const float* wos[4]  = {wo_sa, wo_sb, wo_ca, wo_cb};
  const float* bos[4]  = {bo_sa, bo_sb, bo_ca, bo_cb};
  float csum = 0.f;
  for (int tag = 0; tag < 4; tag++) {
    const float* wfh = Wf + ((tag == 0 || tag == 2) ? 0 : 64);
    float v = 0.f;
    for (int e = 0; e < 64; e++) v += wos[tag][e * 64 + t] * wfh[e];
    v_lds[t] = v;
    __syncthreads();
    for (int h = 0; h < 4; h++) {
      float u = 0.f;
      for (int dp = 0; dp < 16; dp++)
        u += wins[tag][(128 + h * 16 + dp) * 64 + t] * v_lds[h * 16 + dp];
      ws[OFF_U + tag * 256 + h * 64 + t] = u;
    }
    if (t < 4) {
      float cv = 0.f;
      for (int dp = 0; dp < 16; dp++)
        cv += bins[tag][128 + t * 16 + dp] * v_lds[t * 16 + dp];
      ws[OFF_CV + tag * 4 + t] = cv;
    }
    if (t == 0) {
      float c = 0.f;
      for (int e = 0; e < 64; e++) c += bos[tag][e] * wfh[e];
      csum += c;
    }
    __syncthreads();
  }
  if (t == 0) ws[OFF_CONST] = 0.5f * csum + bf[0];
}

// ---------------------------------------------------------------- prep 2: pack
__global__ __launch_bounds__(256) void prep_pack(
    const float* __restrict__ w2, const float* __restrict__ w3,
    const float* __restrict__ win_sa, const float* __restrict__ win_sb,
    const float* __restrict__ win_ca, const float* __restrict__ win_cb,
    const float* __restrict__ bin_sa, const float* __restrict__ bin_sb,
    const float* __restrict__ bin_ca, const float* __restrict__ bin_cb,
    float* __restrict__ ws, u16* __restrict__ w2bf, u16* __restrict__ w3bf,
    u16* __restrict__ WA, u16* __restrict__ WB) {
  int idx = blockIdx.x * 256 + threadIdx.x;
  if (idx < 131072) {
    w2bf[idx] = f2bf(w2[idx]);
  } else if (idx < 196608) {
    int i = idx - 131072;
    w3bf[i] = f2bf(w3[i]);
  } else if (idx < 214016) {        // WA [272][64]
    int i = idx - 196608, n = i >> 6, k = i & 63;
    float v;
    if (n < 64)       v = win_sa[n * 64 + k] * 0.25f;          // q_sa
    else if (n < 128) v = win_sa[n * 64 + k];                  // k_sa
    else if (n < 192) v = win_ca[(n - 128) * 64 + k] * 0.25f;  // q_ca
    else if (n < 256) v = win_cb[(n - 128) * 64 + k];          // k_cb
    else if (n < 260) v = ws[OFF_U + 0 * 256 + (n - 256) * 64 + k];  // u_sa
    else if (n < 264) v = ws[OFF_U + 3 * 256 + (n - 260) * 64 + k];  // u_cb
    else              v = 0.f;
    WA[i] = f2bf(v);
  } else if (idx < 231424) {        // WB [272][64]
    int i = idx - 214016, n = i >> 6, k = i & 63;
    float v;
    if (n < 64)       v = win_sb[n * 64 + k] * 0.25f;          // q_sb
    else if (n < 128) v = win_sb[n * 64 + k];                  // k_sb
    else if (n < 192) v = win_cb[(n - 128) * 64 + k] * 0.25f;  // q_cb
    else if (n < 256) v = win_ca[(n - 128) * 64 + k];          // k_ca
    else if (n < 260) v = ws[OFF_U + 1 * 256 + (n - 256) * 64 + k];  // u_sb
    else if (n < 264) v = ws[OFF_U + 2 * 256 + (n - 260) * 64 + k];  // u_ca
    else              v = 0.f;
    WB[i] = f2bf(v);
  } else if (idx < 231696) {        // bA
    int n = idx - 231424;
    float v;
    if (n < 64)       v = bin_sa[n] * 0.25f;
    else if (n < 128) v = bin_sa[n];
    else if (n < 192) v = bin_ca[n - 128] * 0.25f;
    else if (n < 256) v = bin_cb[n - 128];
    else if (n < 260) v = ws[OFF_CV + 0 * 4 + (n - 256)];
    else if (n < 264) v = ws[OFF_CV + 3 * 4 + (n - 260)];
    else              v = 0.f;
    ws[OFF_BA + n] = v;
  } else if (idx < 231968) {        // bB
    int n = idx - 231696;
    float v;
    if (n < 64)       v = bin_sb[n] * 0.25f;
    else if (n < 128) v = bin_sb[n];
    else if (n < 192) v = bin_cb[n - 128] * 0.25f;
    else if (n < 256) v = bin_ca[n - 128];
    else if (n < 260) v = ws[OFF_CV + 1 * 4 + (n - 256)];
    else if (n < 264) v = ws[OFF_CV + 2 * 4 + (n - 260)];
    else              v = 0.f;
    ws[OFF_BB + n] = v;
  }
}

// ---------------------------------------------------------------- tokens (MFMA)
// grid = (B/64) * 8 blocks: block = 64 elements x ONE d (d = blockIdx & 7 so
// round-robin XCD dispatch localizes each d's weights in one XCD's L2/L1).
// 4 waves x wave-private 16-row tiles, ZERO barriers (all LDS wave-private).
__global__ __launch_bounds__(256) void tokens_kernel(
    const float* __restrict__ x, const float* __restrict__ w1,
    const float* __restrict__ b1, const float* __restrict__ b2,
    const float* __restrict__ b3, const u16* __restrict__ w2bf,
    const u16* __restrict__ w3bf, u16* __restrict__ tok_out) {
  __shared__ __align__(16) u16 h2s[4][16 * 136];
  __shared__ __align__(16) u16 stg[4][16 * 72];
  const int t = threadIdx.x;
  const int wave = t >> 6, lane = t & 63;
  const int m15 = lane & 15, quad = lane >> 4;
  const int d = blockIdx.x & 7;
  const int b0 = (blockIdx.x >> 3) * 64 + wave * 16;  // this wave's 16 rows
  const float xv = x[(size_t)(b0 + m15) * 8 + d];

  // ---- h1 -> A-frags (A[m=lane&15][k=quad*8+j])
  short8 afr[4];
#pragma unroll
  for (int ks = 0; ks < 4; ks++) {
    const float* w1p = w1 + d * 128 + ks * 32 + quad * 8;
    const float* b1p = b1 + d * 128 + ks * 32 + quad * 8;
    float4 wa = *(const float4*)w1p, wb = *(const float4*)(w1p + 4);
    float4 ba = *(const float4*)b1p, bb = *(const float4*)(b1p + 4);
    short8 a;
    a[0] = (short)f2bf(__sinf(xv * wa.x + ba.x));
    a[1] = (short)f2bf(__sinf(xv * wa.y + ba.y));
    a[2] = (short)f2bf(__sinf(xv * wa.z + ba.z));
    a[3] = (short)f2bf(__sinf(xv * wa.w + ba.w));
    a[4] = (short)f2bf(__sinf(xv * wb.x + bb.x));
    a[5] = (short)f2bf(__sinf(xv * wb.y + bb.y));
    a[6] = (short)f2bf(__sinf(xv * wb.z + bb.z));
    a[7] = (short)f2bf(__sinf(xv * wb.w + bb.w));
    afr[ks] = a;
  }
  // ---- layer2: [16,128] @ [128,128]
  f32x4 acc2[8];
#pragma unroll
  for (int nt = 0; nt < 8; nt++) acc2[nt] = (f32x4){0.f, 0.f, 0.f, 0.f};
#pragma unroll
  for (int ks = 0; ks < 4; ks++) {
    const u16* bp = w2bf + d * 16384 + m15 * 128 + ks * 32 + quad * 8;
#pragma unroll
    for (int nt = 0; nt < 8; nt++) {
      short8 bfr = *(const short8*)(bp + nt * 2048);
      acc2[nt] = __builtin_amdgcn_mfma_f32_16x16x32_bf16(afr[ks], bfr, acc2[nt], 0, 0, 0);
    }
  }
  // ---- ep2 -> wave-private h2s (C layout: col=m15, row=quad*4+r)
#pragma unroll
  for (int nt = 0; nt < 8; nt++) {
    float bias = b2[d * 128 + m15 + 16 * nt];
#pragma unroll
    for (int r = 0; r < 4; r++)
      h2s[wave][(quad * 4 + r) * 136 + m15 + 16 * nt] = f2bf(__sinf(acc2[nt][r] + bias));
  }
  // ---- layer3: [16,128] @ [128,64]
  f32x4 acc3[4];
#pragma unroll
  for (int nt = 0; nt < 4; nt++) acc3[nt] = (f32x4){0.f, 0.f, 0.f, 0.f};
#pragma unroll
  for (int ks = 0; ks < 4; ks++) {
    short8 af = *(const short8*)(&h2s[wave][m15 * 136 + ks * 32 + quad * 8]);
    const u16* bp3 = w3bf + d * 8192 + m15 * 128 + ks * 32 + quad * 8;
#pragma unroll
    for (int nt = 0; nt < 4; nt++) {
      short8 bfr = *(const short8*)(bp3 + nt * 2048);
      acc3[nt] = __builtin_amdgcn_mfma_f32_16x16x32_bf16(af, bfr, acc3[nt], 0, 0, 0);
    }
  }
  // ---- ep3: wave-private staging, then coalesced 16B stores (no barrier)
#pragma unroll
  for (int nt = 0; nt < 4; nt++) {
    float bias = b3[d * 64 + m15 + 16 * nt];
#pragma unroll
    for (int r = 0; r < 4; r++)
      stg[wave][(quad * 4 + r) * 72 + m15 + 16 * nt] = f2bf(acc3[nt][r] + bias);
  }
  {
    int row_l = lane >> 2;
#pragma unroll
    for (int it = 0; it < 2; it++) {
      int chunk = (lane & 3) + it * 4;
      short8 v = *(const short8*)&stg[wave][row_l * 72 + chunk * 8];
      *(short8*)(tok_out + ((size_t)(b0 + row_l) * 8 + d) * 64 + chunk * 8) = v;
    }
  }
}

// ---------------------------------------------------------------- attention (MFMA proj)
// block = 256 thr / 8 elems. Stage A: 4 waves x one 16-row M-tile, W-frags
// 4-deep software-prefetched. Stage B: VALU softmax on bf16 P in LDS.
__global__ __launch_bounds__(256) void attn_kernel(
    const float* __restrict__ ws, const u16* __restrict__ tok,
    const u16* __restrict__ WA, const u16* __restrict__ WB,
    float* __restrict__ out) {
  __shared__ __align__(16) u16 tokl[8 * TOKL_STRIDE];
  __shared__ __align__(16) u16 P[2 * PSIDE];
  const int t = threadIdx.x;
  const int b0 = blockIdx.x * 8;
  {  // tokens -> LDS (padded per-elem stride)
    const short8* g = (const short8*)(tok + (size_t)b0 * 512);
#pragma unroll
    for (int it = 0; it < 2; it++) {
      int c = t + it * 256;
      short8 v = g[c];
      *(short8*)&tokl[(c >> 6) * TOKL_STRIDE + (c & 63) * 8] = v;
    }
  }
  __syncthreads();
  const int wave = t >> 6, lane = t & 63;
  const int m15 = lane & 15, quad = lane >> 4;
  {  // stage A: P = tok @ W (+bias), bf16, 4-deep W prefetch
    const int side = wave >> 1, mt = wave & 1;
    const u16* W = side ? WB : WA;
    const float* bias = ws + (side ? OFF_BB : OFF_BA);
    const int e = mt * 4 + (m15 >> 2);
    const int dd = (m15 & 3) + side * 4;
    const u16* abase = &tokl[e * TOKL_STRIDE + dd * 64 + quad * 8];
    short8 a0 = *(const short8*)(abase);
    short8 a1 = *(const short8*)(abase + 32);
    u16* Pb = &P[side * PSIDE];
    const int rowc = mt * 16 + quad * 4;
    short8 wf0[4], wf1[4];
#pragma unroll
    for (int i = 0; i < 4; i++) {
      const u16* bp = W + (i * 16 + m15) * 64 + quad * 8;
      wf0[i] = *(const short8*)bp;
      wf1[i] = *(const short8*)(bp + 32);
    }
#pragma unroll
    for (int nt = 0; nt < 17; nt++) {
      short8 bf0 = wf0[nt & 3];
      short8 bf1 = wf1[nt & 3];
      if (nt + 4 < 17) {
        const u16* bp = W + ((nt + 4) * 16 + m15) * 64 + quad * 8;
        wf0[nt & 3] = *(const short8*)bp;
        wf1[nt & 3] = *(const short8*)(bp + 32);
      }
      f32x4 acc = {0.f, 0.f, 0.f, 0.f};
      acc = __builtin_amdgcn_mfma_f32_16x16x32_bf16(a0, bf0, acc, 0, 0, 0);
      acc = __builtin_amdgcn_mfma_f32_16x16x32_bf16(a1, bf1, acc, 0, 0, 0);
      float bi = bias[nt * 16 + m15];
#pragma unroll
      for (int r = 0; r < 4; r++)
        Pb[(rowc + r) * P_STRIDE + m15 + 16 * nt] = f2bf(acc[r] + bi);
    }
  }
  __syncthreads();
  // stage B: softmax + folded-V mix
  const float cst = ws[OFF_CONST];
  const int elem = t >> 5, sub = t & 31;
  const int tb = sub >> 4, h = (sub >> 2) & 3, q = sub & 3;
  float acc = 0.f;
#pragma unroll
  for (int ti = 0; ti < 2; ti++) {
    const int tag = tb + ti * 2;
    const int qs = tag & 1, cross = tag >> 1;
    const int ks2 = qs ^ cross;
    const u16* Pq = P + qs * PSIDE + (elem * 4 + q) * P_STRIDE + cross * 128 + h * 16;
    float qv[16];
    ld16(Pq, qv);
    const u16* Pk = P + ks2 * PSIDE + (elem * 4) * P_STRIDE + 64 + cross * 128 + h * 16;
    float sc[4];
#pragma unroll
    for (int k = 0; k < 4; k++) {
      float kv[16];
      ld16(Pk + k * P_STRIDE, kv);
      float s = 0.f;
#pragma unroll
      for (int i = 0; i < 16; i++) s += qv[i] * kv[i];
      sc[k] = s;
    }
    float mx = fmaxf(fmaxf(sc[0], sc[1]), fmaxf(sc[2], sc[3]));
    float e0 = __expf(sc[0] - mx), e1 = __expf(sc[1] - mx);
    float e2 = __expf(sc[2] - mx), e3 = __expf(sc[3] - mx);
    const u16* Psv = P + ks2 * PSIDE + (elem * 4) * P_STRIDE + 256 + cross * 4 + h;
    float o = e0 * bf2f(Psv[0]) + e1 * bf2f(Psv[P_STRIDE]) +
              e2 * bf2f(Psv[2 * P_STRIDE]) + e3 * bf2f(Psv[3 * P_STRIDE]);
    acc += o / (e0 + e1 + e2 + e3);
  }
  acc += __shfl_xor(acc, 1);
  acc += __shfl_xor(acc, 2);
  acc += __shfl_xor(acc, 4);
  acc += __shfl_xor(acc, 8);
  acc += __shfl_xor(acc, 16);
  if (sub == 0) {
    float val = 0.125f * acc + cst;
    out[b0 + elem] = val > 0.f ? val : 0.01f * val;
  }
}

// ---------------------------------------------------------------- launch
extern "C" void kernel_launch(void* const* d_in, const int* in_sizes, int n_in,
                              void* d_out, int out_size, void* d_ws, size_t ws_size,
                              hipStream_t stream) {
  const float* x      = (const float*)d_in[0];
  const float* w1     = (const float*)d_in[1];
  const float* b1     = (const float*)d_in[2];
  const float* w2     = (const float*)d_in[3];
  const float* b2     = (const float*)d_in[4];
  const float* w3     = (const float*)d_in[5];
  const float* b3     = (const float*)d_in[6];
  const float* win_sa = (const float*)d_in[7];
  const float* bin_sa = (const float*)d_in[8];
  const float* wo_sa  = (const float*)d_in[9];
  const float* bo_sa  = (const float*)d_in[10];
  const float* win_sb = (const float*)d_in[11];
  const float* bin_sb = (const float*)d_in[12];
  const float* wo_sb  = (const float*)d_in[13];
  const float* bo_sb  = (const float*)d_in[14];
  const float* win_ca = (const float*)d_in[15];
  const float* bin_ca = (const float*)d_in[16];
  const float* wo_ca  = (const float*)d_in[17];
  const float* bo_ca  = (const float*)d_in[18];
  const float* win_cb = (const float*)d_in[19];
  const float* bin_cb = (const float*)d_in[20];
  const float* wo_cb  = (const float*)d_in[21];
  const float* bo_cb  = (const float*)d_in[22];
  const float* Wf     = (const float*)d_in[23];
  const float* bf     = (const float*)d_in[24];
  float* ws = (float*)d_ws;
  u16* WAp    = (u16*)((char*)d_ws + OFF_WA_B);
  u16* WBp    = (u16*)((char*)d_ws + OFF_WB_B);
  u16* w2bf   = (u16*)((char*)d_ws + OFF_W2BF_B);
  u16* w3bf   = (u16*)((char*)d_ws + OFF_W3BF_B);
  u16* tokbuf = (u16*)((char*)d_ws + OFF_TOK_B);
  float* out = (float*)d_out;

  prep_fold<<<1, 64, 0, stream>>>(win_sa, bin_sa, wo_sa, bo_sa,
                                  win_sb, bin_sb, wo_sb, bo_sb,
                                  win_ca, bin_ca, wo_ca, bo_ca,
                                  win_cb, bin_cb, wo_cb, bo_cb,
                                  Wf, bf, ws);
  prep_pack<<<907, 256, 0, stream>>>(w2, w3, win_sa, win_sb, win_ca, win_cb,
                                     bin_sa, bin_sb, bin_ca, bin_cb,
                                     ws, w2bf, w3bf, WAp, WBp);
  tokens_kernel<<<8192, 256, 0, stream>>>(x, w1, b1, b2, b3, w2bf, w3bf, tokbuf);
  attn_kernel<<<65536 / 8, 256, 0, stream>>>(ws, tokbuf, WAp, WBp, out);
}

// Round 6
// 302.091 us; speedup vs baseline: 3.4590x; 1.4580x over previous
//
#include <hip/hip_runtime.h>

typedef unsigned short u16;
typedef __attribute__((ext_vector_type(8))) short short8;
typedef __attribute__((ext_vector_type(4))) float f32x4;

// ws float-index offsets
#define OFF_U     0       // [4][4][64] folded value vectors (tag,h,k)
#define OFF_CV    1024    // [4][4]
#define OFF_CONST 1040
#define OFF_BA    1056    // [272] fp32 bias for WA cols
#define OFF_BB    1328    // [272]
// ws byte offsets (16B-aligned)
#define OFF_WA_B    6400     // u16 [272][64]
#define OFF_WB_B    41216    // u16 [272][64]
#define OFF_W2BF_B  76032    // u16 [8][128][128]
#define OFF_W3BF_B  338176   // u16 [8][64][128]
#define OFF_TOK_B   469248   // u16 tokens [B][8][64]

#define P_STRIDE 280
#define PSIDE    (32 * P_STRIDE)
#define TOKL_STRIDE 520

static __device__ __forceinline__ u16 f2bf(float f) {
  unsigned int bits = __float_as_uint(f);
  bits += 0x7fffu + ((bits >> 16) & 1u);
  return (u16)(bits >> 16);
}
static __device__ __forceinline__ float bf2f(u16 u) {
  return __uint_as_float(((unsigned int)u) << 16);
}
static __device__ __forceinline__ void ld16(const u16* p, float* o) {
  short8 v0 = *(const short8*)p;
  short8 v1 = *(const short8*)(p + 8);
#pragma unroll
  for (int i = 0; i < 8; i++) {
    o[i] = bf2f((u16)v0[i]);
    o[8 + i] = bf2f((u16)v1[i]);
  }
}

// ---------------------------------------------------------------- prep 1: fold
__global__ __launch_bounds__(64) void prep_fold(
    const float* __restrict__ win_sa, const float* __restrict__ bin_sa,
    const float* __restrict__ wo_sa,  const float* __restrict__ bo_sa,
    const float* __restrict__ win_sb, const float* __restrict__ bin_sb,
    const float* __restrict__ wo_sb,  const float* __restrict__ bo_sb,
    const float* __restrict__ win_ca, const float* __restrict__ bin_ca,
    const float* __restrict__ wo_ca,  const float* __restrict__ bo_ca,
    const float* __restrict__ win_cb, const float* __restrict__ bin_cb,
    const float* __restrict__ wo_cb,  const float* __restrict__ bo_cb,
    const float* __restrict__ Wf, const float* __restrict__ bf,
    float* __restrict__ ws) {
  __shared__ float v_lds[64];
  const int t = threadIdx.x;  // 0..63
  const float* wins[4] = {win_sa, win_sb, win_ca, win_cb};
  const float* bins[4] = {bin_sa, bin_sb, bin_ca, bin_cb};
  const float* wos[4]  = {wo_sa, wo_sb, wo_ca, wo_cb};
  const float* bos[4]  = {bo_sa, bo_sb, bo_ca, bo_cb};
  float csum = 0.f;
  for (int tag = 0; tag < 4; tag++) {
    const float* wfh = Wf + ((tag == 0 || tag == 2) ? 0 : 64);
    float v = 0.f;
    for (int e = 0; e < 64; e++) v += wos[tag][e * 64 + t] * wfh[e];
    v_lds[t] = v;
    __syncthreads();
    for (int h = 0; h < 4; h++) {
      float u = 0.f;
      for (int dp = 0; dp < 16; dp++)
        u += wins[tag][(128 + h * 16 + dp) * 64 + t] * v_lds[h * 16 + dp];
      ws[OFF_U + tag * 256 + h * 64 + t] = u;
    }
    if (t < 4) {
      float cv = 0.f;
      for (int dp = 0; dp < 16; dp++)
        cv += bins[tag][128 + t * 16 + dp] * v_lds[t * 16 + dp];
      ws[OFF_CV + tag * 4 + t] = cv;
    }
    if (t == 0) {
      float c = 0.f;
      for (int e = 0; e < 64; e++) c += bos[tag][e] * wfh[e];
      csum += c;
    }
    __syncthreads();
  }
  if (t == 0) ws[OFF_CONST] = 0.5f * csum + bf[0];
}

// ---------------------------------------------------------------- prep 2: pack
__global__ __launch_bounds__(256) void prep_pack(
    const float* __restrict__ w2, const float* __restrict__ w3,
    const float* __restrict__ win_sa, const float* __restrict__ win_sb,
    const float* __restrict__ win_ca, const float* __restrict__ win_cb,
    const float* __restrict__ bin_sa, const float* __restrict__ bin_sb,
    const float* __restrict__ bin_ca, const float* __restrict__ bin_cb,
    float* __restrict__ ws, u16* __restrict__ w2bf, u16* __restrict__ w3bf,
    u16* __restrict__ WA, u16* __restrict__ WB) {
  int idx = blockIdx.x * 256 + threadIdx.x;
  if (idx < 131072) {
    w2bf[idx] = f2bf(w2[idx]);
  } else if (idx < 196608) {
    int i = idx - 131072;
    w3bf[i] = f2bf(w3[i]);
  } else if (idx < 214016) {        // WA [272][64]
    int i = idx - 196608, n = i >> 6, k = i & 63;
    float v;
    if (n < 64)       v = win_sa[n * 64 + k] * 0.25f;          // q_sa
    else if (n < 128) v = win_sa[n * 64 + k];                  // k_sa
    else if (n < 192) v = win_ca[(n - 128) * 64 + k] * 0.25f;  // q_ca
    else if (n < 256) v = win_cb[(n - 128) * 64 + k];          // k_cb
    else if (n < 260) v = ws[OFF_U + 0 * 256 + (n - 256) * 64 + k];  // u_sa
    else if (n < 264) v = ws[OFF_U + 3 * 256 + (n - 260) * 64 + k];  // u_cb
    else              v = 0.f;
    WA[i] = f2bf(v);
  } else if (idx < 231424) {        // WB [272][64]
    int i = idx - 214016, n = i >> 6, k = i & 63;
    float v;
    if (n < 64)       v = win_sb[n * 64 + k] * 0.25f;          // q_sb
    else if (n < 128) v = win_sb[n * 64 + k];                  // k_sb
    else if (n < 192) v = win_cb[(n - 128) * 64 + k] * 0.25f;  // q_cb
    else if (n < 256) v = win_ca[(n - 128) * 64 + k];          // k_ca
    else if (n < 260) v = ws[OFF_U + 1 * 256 + (n - 256) * 64 + k];  // u_sb
    else if (n < 264) v = ws[OFF_U + 2 * 256 + (n - 260) * 64 + k];  // u_ca
    else              v = 0.f;
    WB[i] = f2bf(v);
  } else if (idx < 231696) {        // bA
    int n = idx - 231424;
    float v;
    if (n < 64)       v = bin_sa[n] * 0.25f;
    else if (n < 128) v = bin_sa[n];
    else if (n < 192) v = bin_ca[n - 128] * 0.25f;
    else if (n < 256) v = bin_cb[n - 128];
    else if (n < 260) v = ws[OFF_CV + 0 * 4 + (n - 256)];
    else if (n < 264) v = ws[OFF_CV + 3 * 4 + (n - 260)];
    else              v = 0.f;
    ws[OFF_BA + n] = v;
  } else if (idx < 231968) {        // bB
    int n = idx - 231696;
    float v;
    if (n < 64)       v = bin_sb[n] * 0.25f;
    else if (n < 128) v = bin_sb[n];
    else if (n < 192) v = bin_cb[n - 128] * 0.25f;
    else if (n < 256) v = bin_ca[n - 128];
    else if (n < 260) v = ws[OFF_CV + 1 * 4 + (n - 256)];
    else if (n < 264) v = ws[OFF_CV + 2 * 4 + (n - 260)];
    else              v = 0.f;
    ws[OFF_BB + n] = v;
  }
}

// ---------------------------------------------------------------- tokens (MFMA, persistent wave)
// grid = 4096 single-wave blocks, d = blockIdx & 7 (XCD-local weights).
// Layer2 B-frags + biases hoisted into registers ONCE; loop over 8 tiles.
__global__ __launch_bounds__(64, 2) void tokens_kernel(
    const float* __restrict__ x, const float* __restrict__ w1,
    const float* __restrict__ b1, const float* __restrict__ b2,
    const float* __restrict__ b3, const u16* __restrict__ w2bf,
    const u16* __restrict__ w3bf, u16* __restrict__ tok_out) {
  __shared__ __align__(16) u16 h2s[16 * 136];
  __shared__ __align__(16) u16 stg[16 * 72];
  const int lane = threadIdx.x;
  const int m15 = lane & 15, quad = lane >> 4;
  const int d = blockIdx.x & 7;
  const int g = blockIdx.x >> 3;  // 0..511

  // hoist layer2 B-operand for this lane: 32 x short8 (128 VGPR)
  short8 w2f[4][8];
#pragma unroll
  for (int ks = 0; ks < 4; ks++)
#pragma unroll
    for (int nt = 0; nt < 8; nt++)
      w2f[ks][nt] = *(const short8*)(w2bf + d * 16384 + m15 * 128 + ks * 32 +
                                     quad * 8 + nt * 2048);
  float b2v[8], b3v[4];
#pragma unroll
  for (int nt = 0; nt < 8; nt++) b2v[nt] = b2[d * 128 + m15 + 16 * nt];
#pragma unroll
  for (int nt = 0; nt < 4; nt++) b3v[nt] = b3[d * 64 + m15 + 16 * nt];

  for (int i = 0; i < 8; i++) {
    const int b0 = (g * 8 + i) * 16;
    const float xv = x[(size_t)(b0 + m15) * 8 + d];
    // ---- h1 -> A-frags (A[m=lane&15][k=quad*8+j]); w1/b1 from L1
    short8 afr[4];
#pragma unroll
    for (int ks = 0; ks < 4; ks++) {
      const float* w1p = w1 + d * 128 + ks * 32 + quad * 8;
      const float* b1p = b1 + d * 128 + ks * 32 + quad * 8;
      float4 wa = *(const float4*)w1p, wb = *(const float4*)(w1p + 4);
      float4 ba = *(const float4*)b1p, bb = *(const float4*)(b1p + 4);
      short8 a;
      a[0] = (short)f2bf(__sinf(xv * wa.x + ba.x));
      a[1] = (short)f2bf(__sinf(xv * wa.y + ba.y));
      a[2] = (short)f2bf(__sinf(xv * wa.z + ba.z));
      a[3] = (short)f2bf(__sinf(xv * wa.w + ba.w));
      a[4] = (short)f2bf(__sinf(xv * wb.x + bb.x));
      a[5] = (short)f2bf(__sinf(xv * wb.y + bb.y));
      a[6] = (short)f2bf(__sinf(xv * wb.z + bb.z));
      a[7] = (short)f2bf(__sinf(xv * wb.w + bb.w));
      afr[ks] = a;
    }
    // ---- layer2: [16,128] @ [128,128], B from registers
    f32x4 acc2[8];
#pragma unroll
    for (int nt = 0; nt < 8; nt++) acc2[nt] = (f32x4){0.f, 0.f, 0.f, 0.f};
#pragma unroll
    for (int ks = 0; ks < 4; ks++)
#pragma unroll
      for (int nt = 0; nt < 8; nt++)
        acc2[nt] = __builtin_amdgcn_mfma_f32_16x16x32_bf16(afr[ks], w2f[ks][nt],
                                                           acc2[nt], 0, 0, 0);
    // ---- ep2 -> h2s (C layout: col=m15, row=quad*4+r)
#pragma unroll
    for (int nt = 0; nt < 8; nt++) {
#pragma unroll
      for (int r = 0; r < 4; r++)
        h2s[(quad * 4 + r) * 136 + m15 + 16 * nt] =
            f2bf(__sinf(acc2[nt][r] + b2v[nt]));
    }
    // ---- layer3: [16,128] @ [128,64]; w3 streamed (L1-resident, same addrs every iter)
    f32x4 acc3[4];
#pragma unroll
    for (int nt = 0; nt < 4; nt++) acc3[nt] = (f32x4){0.f, 0.f, 0.f, 0.f};
#pragma unroll
    for (int ks = 0; ks < 4; ks++) {
      short8 af = *(const short8*)(&h2s[m15 * 136 + ks * 32 + quad * 8]);
      const u16* bp3 = w3bf + d * 8192 + m15 * 128 + ks * 32 + quad * 8;
#pragma unroll
      for (int nt = 0; nt < 4; nt++) {
        short8 bfr = *(const short8*)(bp3 + nt * 2048);
        acc3[nt] = __builtin_amdgcn_mfma_f32_16x16x32_bf16(af, bfr, acc3[nt], 0, 0, 0);
      }
    }
    // ---- ep3: wave-private staging, coalesced 16B stores
#pragma unroll
    for (int nt = 0; nt < 4; nt++) {
#pragma unroll
      for (int r = 0; r < 4; r++)
        stg[(quad * 4 + r) * 72 + m15 + 16 * nt] = f2bf(acc3[nt][r] + b3v[nt]);
    }
    {
      int row_l = lane >> 2;
#pragma unroll
      for (int it = 0; it < 2; it++) {
        int chunk = (lane & 3) + it * 4;
        short8 v = *(const short8*)&stg[row_l * 72 + chunk * 8];
        *(short8*)(tok_out + ((size_t)(b0 + row_l) * 8 + d) * 64 + chunk * 8) = v;
      }
    }
  }
}

// ---------------------------------------------------------------- attention (persistent, W in regs)
// grid = 512 blocks x 16 el-groups. Per-lane W-frags (34 short8) + biases
// hoisted into registers once; tokens double-buffered in LDS w/ reg prefetch.
__global__ __launch_bounds__(256, 2) void attn_kernel(
    const float* __restrict__ ws, const u16* __restrict__ tok,
    const u16* __restrict__ WA, const u16* __restrict__ WB,
    float* __restrict__ out) {
  __shared__ __align__(16) u16 tokl[2][8 * TOKL_STRIDE];
  __shared__ __align__(16) u16 P[2 * PSIDE];
  const int t = threadIdx.x;
  const int wave = t >> 6, lane = t & 63;
  const int m15 = lane & 15, quad = lane >> 4;
  const int side = wave >> 1, mt = wave & 1;
  const float cst = ws[OFF_CONST];

  // hoist W-frags + bias for this lane (iteration-invariant)
  const u16* W = side ? WB : WA;
  const float* bias = ws + (side ? OFF_BB : OFF_BA);
  short8 wf0[17], wf1[17];
  float biasv[17];
#pragma unroll
  for (int nt = 0; nt < 17; nt++) {
    const u16* bp = W + (nt * 16 + m15) * 64 + quad * 8;
    wf0[nt] = *(const short8*)bp;
    wf1[nt] = *(const short8*)(bp + 32);
    biasv[nt] = bias[nt * 16 + m15];
  }
  // stage-A fixed geometry
  const int e = mt * 4 + (m15 >> 2);
  const int dd = (m15 & 3) + side * 4;
  const int rowc = mt * 16 + quad * 4;
  u16* Pb = &P[side * PSIDE];
  // stage-B fixed geometry
  const int elem = t >> 5, sub = t & 31;
  const int tb = sub >> 4, h = (sub >> 2) & 3, q = sub & 3;

  // prefetch iteration 0 tokens
  short8 tv0, tv1;
  {
    const short8* g = (const short8*)(tok + (size_t)(blockIdx.x * 16) * 8 * 512);
    tv0 = g[t];
    tv1 = g[t + 256];
  }
  int buf = 0;
  for (int it = 0; it < 16; it++) {
    const int b0el = blockIdx.x * 128 + it * 8;
    // stage tokens into LDS buffer
    {
      int c0 = t, c1 = t + 256;
      *(short8*)&tokl[buf][(c0 >> 6) * TOKL_STRIDE + (c0 & 63) * 8] = tv0;
      *(short8*)&tokl[buf][(c1 >> 6) * TOKL_STRIDE + (c1 & 63) * 8] = tv1;
    }
    // prefetch next iteration's tokens (hidden under stage A+B)
    if (it + 1 < 16) {
      const short8* g = (const short8*)(tok + (size_t)(b0el + 8) * 512);
      tv0 = g[t];
      tv1 = g[t + 256];
    }
    __syncthreads();
    // ---- stage A: P = tok @ W (+bias), W from registers
    {
      const u16* abase = &tokl[buf][e * TOKL_STRIDE + dd * 64 + quad * 8];
      short8 a0 = *(const short8*)(abase);
      short8 a1 = *(const short8*)(abase + 32);
#pragma unroll
      for (int nt = 0; nt < 17; nt++) {
        f32x4 acc = {0.f, 0.f, 0.f, 0.f};
        acc = __builtin_amdgcn_mfma_f32_16x16x32_bf16(a0, wf0[nt], acc, 0, 0, 0);
        acc = __builtin_amdgcn_mfma_f32_16x16x32_bf16(a1, wf1[nt], acc, 0, 0, 0);
#pragma unroll
        for (int r = 0; r < 4; r++)
          Pb[(rowc + r) * P_STRIDE + m15 + 16 * nt] = f2bf(acc[r] + biasv[nt]);
      }
    }
    __syncthreads();
    // ---- stage B: softmax + folded-V mix
    float acc = 0.f;
#pragma unroll
    for (int ti = 0; ti < 2; ti++) {
      const int tag = tb + ti * 2;
      const int qs = tag & 1, cross = tag >> 1;
      const int ks2 = qs ^ cross;
      const u16* Pq = P + qs * PSIDE + (elem * 4 + q) * P_STRIDE + cross * 128 + h * 16;
      float qv[16];
      ld16(Pq, qv);
      const u16* Pk = P + ks2 * PSIDE + (elem * 4) * P_STRIDE + 64 + cross * 128 + h * 16;
      float sc[4];
#pragma unroll
      for (int k = 0; k < 4; k++) {
        float kv[16];
        ld16(Pk + k * P_STRIDE, kv);
        float s = 0.f;
#pragma unroll
        for (int i = 0; i < 16; i++) s += qv[i] * kv[i];
        sc[k] = s;
      }
      float mx = fmaxf(fmaxf(sc[0], sc[1]), fmaxf(sc[2], sc[3]));
      float e0 = __expf(sc[0] - mx), e1 = __expf(sc[1] - mx);
      float e2 = __expf(sc[2] - mx), e3 = __expf(sc[3] - mx);
      const u16* Psv = P + ks2 * PSIDE + (elem * 4) * P_STRIDE + 256 + cross * 4 + h;
      float o = e0 * bf2f(Psv[0]) + e1 * bf2f(Psv[P_STRIDE]) +
                e2 * bf2f(Psv[2 * P_STRIDE]) + e3 * bf2f(Psv[3 * P_STRIDE]);
      acc += o / (e0 + e1 + e2 + e3);
    }
    acc += __shfl_xor(acc, 1);
    acc += __shfl_xor(acc, 2);
    acc += __shfl_xor(acc, 4);
    acc += __shfl_xor(acc, 8);
    acc += __shfl_xor(acc, 16);
    if (sub == 0) {
      float val = 0.125f * acc + cst;
      out[b0el + elem] = val > 0.f ? val : 0.01f * val;
    }
    buf ^= 1;
  }
}

// ---------------------------------------------------------------- launch
extern "C" void kernel_launch(void* const* d_in, const int* in_sizes, int n_in,
                              void* d_out, int out_size, void* d_ws, size_t ws_size,
                              hipStream_t stream) {
  const float* x      = (const float*)d_in[0];
  const float* w1     = (const float*)d_in[1];
  const float* b1     = (const float*)d_in[2];
  const float* w2     = (const float*)d_in[3];
  const float* b2     = (const float*)d_in[4];
  const float* w3     = (const float*)d_in[5];
  const float* b3     = (const float*)d_in[6];
  const float* win_sa = (const float*)d_in[7];
  const float* bin_sa = (const float*)d_in[8];
  const float* wo_sa  = (const float*)d_in[9];
  const float* bo_sa  = (const float*)d_in[10];
  const float* win_sb = (const float*)d_in[11];
  const float* bin_sb = (const float*)d_in[12];
  const float* wo_sb  = (const float*)d_in[13];
  const float* bo_sb  = (const float*)d_in[14];
  const float* win_ca = (const float*)d_in[15];
  const float* bin_ca = (const float*)d_in[16];
  const float* wo_ca  = (const float*)d_in[17];
  const float* bo_ca  = (const float*)d_in[18];
  const float* win_cb = (const float*)d_in[19];
  const float* bin_cb = (const float*)d_in[20];
  const float* wo_cb  = (const float*)d_in[21];
  const float* bo_cb  = (const float*)d_in[22];
  const float* Wf     = (const float*)d_in[23];
  const float* bf     = (const float*)d_in[24];
  float* ws = (float*)d_ws;
  u16* WAp    = (u16*)((char*)d_ws + OFF_WA_B);
  u16* WBp    = (u16*)((char*)d_ws + OFF_WB_B);
  u16* w2bf   = (u16*)((char*)d_ws + OFF_W2BF_B);
  u16* w3bf   = (u16*)((char*)d_ws + OFF_W3BF_B);
  u16* tokbuf = (u16*)((char*)d_ws + OFF_TOK_B);
  float* out = (float*)d_out;

  prep_fold<<<1, 64, 0, stream>>>(win_sa, bin_sa, wo_sa, bo_sa,
                                  win_sb, bin_sb, wo_sb, bo_sb,
                                  win_ca, bin_ca, wo_ca, bo_ca,
                                  win_cb, bin_cb, wo_cb, bo_cb,
                                  Wf, bf, ws);
  prep_pack<<<907, 256, 0, stream>>>(w2, w3, win_sa, win_sb, win_ca, win_cb,
                                     bin_sa, bin_sb, bin_ca, bin_cb,
                                     ws, w2bf, w3bf, WAp, WBp);
  tokens_kernel<<<4096, 64, 0, stream>>>(x, w1, b1, b2, b3, w2bf, w3bf, tokbuf);
  attn_kernel<<<512, 256, 0, stream>>>(ws, tokbuf, WAp, WBp, out);
}

// Round 7
// 280.229 us; speedup vs baseline: 3.7289x; 1.0780x over previous
//
#include <hip/hip_runtime.h>

typedef unsigned short u16;
typedef __attribute__((ext_vector_type(8))) short short8;
typedef __attribute__((ext_vector_type(4))) float f32x4;

// ws float-index offsets
#define OFF_U     0       // [4][4][64] folded value vectors (tag,h,k)
#define OFF_CV    1024    // [4][4]
#define OFF_CONST 1040
#define OFF_CTAG  1044    // [4] per-tag bo.wfh sums
#define OFF_BA    1056    // [272] fp32 bias for WA cols
#define OFF_BB    1328    // [272]
// ws byte offsets (16B-aligned)
#define OFF_WA_B    6400     // u16 [272][64]
#define OFF_WB_B    41216    // u16 [272][64]
#define OFF_W2P_B   76032    // u16 [8][32][64][8]  w2 in frag order
#define OFF_W3P_B   338176   // u16 [8][16][64][8]  w3 in frag order
#define OFF_TOK_B   469248   // u16 tokens [B][8][64]

#define P_STRIDE 280
#define PSIDE    (32 * P_STRIDE)
#define TOKL_STRIDE 520

static __device__ __forceinline__ u16 f2bf(float f) {
  unsigned int bits = __float_as_uint(f);
  bits += 0x7fffu + ((bits >> 16) & 1u);
  return (u16)(bits >> 16);
}
static __device__ __forceinline__ float bf2f(u16 u) {
  return __uint_as_float(((unsigned int)u) << 16);
}
static __device__ __forceinline__ void ld16(const u16* p, float* o) {
  short8 v0 = *(const short8*)p;
  short8 v1 = *(const short8*)(p + 8);
#pragma unroll
  for (int i = 0; i < 8; i++) {
    o[i] = bf2f((u16)v0[i]);
    o[8 + i] = bf2f((u16)v1[i]);
  }
}

// ---------------------------------------------------------------- prep 1: fold
// grid = 4 (one tag per block) — R6's single-wave version was latency-bound.
__global__ __launch_bounds__(64) void prep_fold(
    const float* __restrict__ win_sa, const float* __restrict__ bin_sa,
    const float* __restrict__ wo_sa,  const float* __restrict__ bo_sa,
    const float* __restrict__ win_sb, const float* __restrict__ bin_sb,
    const float* __restrict__ wo_sb,  const float* __restrict__ bo_sb,
    const float* __restrict__ win_ca, const float* __restrict__ bin_ca,
    const float* __restrict__ wo_ca,  const float* __restrict__ bo_ca,
    const float* __restrict__ win_cb, const float* __restrict__ bin_cb,
    const float* __restrict__ wo_cb,  const float* __restrict__ bo_cb,
    const float* __restrict__ Wf, float* __restrict__ ws) {
  __shared__ float v_lds[64];
  const int t = threadIdx.x;
  const int tag = blockIdx.x;
  const float* wins[4] = {win_sa, win_sb, win_ca, win_cb};
  const float* bins[4] = {bin_sa, bin_sb, bin_ca, bin_cb};
  const float* wos[4]  = {wo_sa, wo_sb, wo_ca, wo_cb};
  const float* bos[4]  = {bo_sa, bo_sb, bo_ca, bo_cb};
  const float* wfh = Wf + ((tag == 0 || tag == 2) ? 0 : 64);
  float v = 0.f;
#pragma unroll
  for (int e = 0; e < 64; e++) v += wos[tag][e * 64 + t] * wfh[e];
  v_lds[t] = v;
  __syncthreads();
#pragma unroll
  for (int h = 0; h < 4; h++) {
    float u = 0.f;
#pragma unroll
    for (int dp = 0; dp < 16; dp++)
      u += wins[tag][(128 + h * 16 + dp) * 64 + t] * v_lds[h * 16 + dp];
    ws[OFF_U + tag * 256 + h * 64 + t] = u;
  }
  if (t < 4) {
    float cv = 0.f;
#pragma unroll
    for (int dp = 0; dp < 16; dp++)
      cv += bins[tag][128 + t * 16 + dp] * v_lds[t * 16 + dp];
    ws[OFF_CV + tag * 4 + t] = cv;
  }
  if (t == 0) {
    float c = 0.f;
#pragma unroll
    for (int e = 0; e < 64; e++) c += bos[tag][e] * wfh[e];
    ws[OFF_CTAG + tag] = c;
  }
}

// ---------------------------------------------------------------- prep 2: pack
// w2/w3 -> bf16 in per-lane MFMA frag order [d][frag][lane][8]; WA/WB; biases.
__global__ __launch_bounds__(256) void prep_pack(
    const float* __restrict__ w2, const float* __restrict__ w3,
    const float* __restrict__ win_sa, const float* __restrict__ win_sb,
    const float* __restrict__ win_ca, const float* __restrict__ win_cb,
    const float* __restrict__ bin_sa, const float* __restrict__ bin_sb,
    const float* __restrict__ bin_ca, const float* __restrict__ bin_cb,
    const float* __restrict__ bf,
    float* __restrict__ ws, u16* __restrict__ w2p, u16* __restrict__ w3p,
    u16* __restrict__ WA, u16* __restrict__ WB) {
  int idx = blockIdx.x * 256 + threadIdx.x;
  if (idx < 131072) {               // w2p[d][ks*8+nt][lane][j]
    int d = idx >> 14, rem = idx & 16383;
    int f = rem >> 9, ks = f >> 3, nt = f & 7;
    int r2 = rem & 511, l = r2 >> 3, j = r2 & 7;
    int quad = l >> 4, m15 = l & 15;
    w2p[idx] = f2bf(w2[(d * 128 + nt * 16 + m15) * 128 + ks * 32 + quad * 8 + j]);
  } else if (idx < 196608) {        // w3p[d][ks*4+nt][lane][j]
    int i = idx - 131072;
    int d = i >> 13, rem = i & 8191;
    int f = rem >> 9, ks = f >> 2, nt = f & 3;
    int r2 = rem & 511, l = r2 >> 3, j = r2 & 7;
    int quad = l >> 4, m15 = l & 15;
    w3p[i] = f2bf(w3[(d * 64 + nt * 16 + m15) * 128 + ks * 32 + quad * 8 + j]);
  } else if (idx < 214016) {        // WA [272][64]
    int i = idx - 196608, n = i >> 6, k = i & 63;
    float v;
    if (n < 64)       v = win_sa[n * 64 + k] * 0.25f;
    else if (n < 128) v = win_sa[n * 64 + k];
    else if (n < 192) v = win_ca[(n - 128) * 64 + k] * 0.25f;
    else if (n < 256) v = win_cb[(n - 128) * 64 + k];
    else if (n < 260) v = ws[OFF_U + 0 * 256 + (n - 256) * 64 + k];
    else if (n < 264) v = ws[OFF_U + 3 * 256 + (n - 260) * 64 + k];
    else              v = 0.f;
    WA[i] = f2bf(v);
  } else if (idx < 231424) {        // WB [272][64]
    int i = idx - 214016, n = i >> 6, k = i & 63;
    float v;
    if (n < 64)       v = win_sb[n * 64 + k] * 0.25f;
    else if (n < 128) v = win_sb[n * 64 + k];
    else if (n < 192) v = win_cb[(n - 128) * 64 + k] * 0.25f;
    else if (n < 256) v = win_ca[(n - 128) * 64 + k];
    else if (n < 260) v = ws[OFF_U + 1 * 256 + (n - 256) * 64 + k];
    else if (n < 264) v = ws[OFF_U + 2 * 256 + (n - 260) * 64 + k];
    else              v = 0.f;
    WB[i] = f2bf(v);
  } else if (idx < 231696) {        // bA
    int n = idx - 231424;
    float v;
    if (n < 64)       v = bin_sa[n] * 0.25f;
    else if (n < 128) v = bin_sa[n];
    else if (n < 192) v = bin_ca[n - 128] * 0.25f;
    else if (n < 256) v = bin_cb[n - 128];
    else if (n < 260) v = ws[OFF_CV + 0 * 4 + (n - 256)];
    else if (n < 264) v = ws[OFF_CV + 3 * 4 + (n - 260)];
    else              v = 0.f;
    ws[OFF_BA + n] = v;
  } else if (idx < 231968) {        // bB
    int n = idx - 231696;
    float v;
    if (n < 64)       v = bin_sb[n] * 0.25f;
    else if (n < 128) v = bin_sb[n];
    else if (n < 192) v = bin_cb[n - 128] * 0.25f;
    else if (n < 256) v = bin_ca[n - 128];
    else if (n < 260) v = ws[OFF_CV + 1 * 4 + (n - 256)];
    else if (n < 264) v = ws[OFF_CV + 2 * 4 + (n - 260)];
    else              v = 0.f;
    ws[OFF_BB + n] = v;
  } else if (idx == 231968) {       // final constant (prep_fold ran before us)
    ws[OFF_CONST] = 0.5f * (ws[OFF_CTAG] + ws[OFF_CTAG + 1] +
                            ws[OFF_CTAG + 2] + ws[OFF_CTAG + 3]) + bf[0];
  }
}

// ---------------------------------------------------------------- tokens (MFMA)
// grid = 1024: d = blockIdx>>7, g = blockIdx&127 (all 8 d-blocks of a batch
// group share an XCD -> x read once, full-line token writebacks).
// Block stages w2p/w3p[d] (48KB) into LDS once; waves hoist w2 frags to regs.
__global__ __launch_bounds__(256, 2) void tokens_kernel(
    const float* __restrict__ x, const float* __restrict__ w1,
    const float* __restrict__ b1, const float* __restrict__ b2,
    const float* __restrict__ b3, const u16* __restrict__ w2p,
    const u16* __restrict__ w3p, u16* __restrict__ tok_out) {
  __shared__ __align__(16) u16 w2l[16384];
  __shared__ __align__(16) u16 w3l[8192];
  __shared__ __align__(16) u16 h2s[4][16 * 136];
  __shared__ __align__(16) u16 stg[4][16 * 72];
  const int t = threadIdx.x;
  const int wave = t >> 6, lane = t & 63;
  const int m15 = lane & 15, quad = lane >> 4;
  const int d = blockIdx.x >> 7;
  const int g = blockIdx.x & 127;
  // ---- stage weights to LDS (lane-linear, coalesced)
#pragma unroll
  for (int c = 0; c < 8; c++)
    *(short8*)&w2l[c * 2048 + t * 8] = *(const short8*)&w2p[d * 16384 + c * 2048 + t * 8];
#pragma unroll
  for (int c = 0; c < 4; c++)
    *(short8*)&w3l[c * 2048 + t * 8] = *(const short8*)&w3p[d * 8192 + c * 2048 + t * 8];
  __syncthreads();
  // ---- hoist layer2 B-frags to registers (conflict-free b128 LDS reads)
  short8 w2f[4][8];
#pragma unroll
  for (int ks = 0; ks < 4; ks++)
#pragma unroll
    for (int nt = 0; nt < 8; nt++)
      w2f[ks][nt] = *(const short8*)&w2l[(ks * 8 + nt) * 512 + lane * 8];
  float b2v[8], b3v[4];
#pragma unroll
  for (int nt = 0; nt < 8; nt++) b2v[nt] = b2[d * 128 + m15 + 16 * nt];
#pragma unroll
  for (int nt = 0; nt < 4; nt++) b3v[nt] = b3[d * 64 + m15 + 16 * nt];

  for (int i = 0; i < 8; i++) {
    const int b0 = g * 512 + wave * 128 + i * 16;
    const float xv = x[(size_t)(b0 + m15) * 8 + d];
    // ---- h1 -> A-frags
    short8 afr[4];
#pragma unroll
    for (int ks = 0; ks < 4; ks++) {
      const float* w1p = w1 + d * 128 + ks * 32 + quad * 8;
      const float* b1p = b1 + d * 128 + ks * 32 + quad * 8;
      float4 wa = *(const float4*)w1p, wb = *(const float4*)(w1p + 4);
      float4 ba = *(const float4*)b1p, bb = *(const float4*)(b1p + 4);
      short8 a;
      a[0] = (short)f2bf(__sinf(xv * wa.x + ba.x));
      a[1] = (short)f2bf(__sinf(xv * wa.y + ba.y));
      a[2] = (short)f2bf(__sinf(xv * wa.z + ba.z));
      a[3] = (short)f2bf(__sinf(xv * wa.w + ba.w));
      a[4] = (short)f2bf(__sinf(xv * wb.x + bb.x));
      a[5] = (short)f2bf(__sinf(xv * wb.y + bb.y));
      a[6] = (short)f2bf(__sinf(xv * wb.z + bb.z));
      a[7] = (short)f2bf(__sinf(xv * wb.w + bb.w));
      afr[ks] = a;
    }
    // ---- layer2 MFMA, B from registers
    f32x4 acc2[8];
#pragma unroll
    for (int nt = 0; nt < 8; nt++) acc2[nt] = (f32x4){0.f, 0.f, 0.f, 0.f};
#pragma unroll
    for (int ks = 0; ks < 4; ks++)
#pragma unroll
      for (int nt = 0; nt < 8; nt++)
        acc2[nt] = __builtin_amdgcn_mfma_f32_16x16x32_bf16(afr[ks], w2f[ks][nt],
                                                           acc2[nt], 0, 0, 0);
    // ---- ep2 -> wave-private h2s
#pragma unroll
    for (int nt = 0; nt < 8; nt++) {
#pragma unroll
      for (int r = 0; r < 4; r++)
        h2s[wave][(quad * 4 + r) * 136 + m15 + 16 * nt] =
            f2bf(__sinf(acc2[nt][r] + b2v[nt]));
    }
    // ---- layer3 MFMA, B-frags from LDS (lane-linear)
    f32x4 acc3[4];
#pragma unroll
    for (int nt = 0; nt < 4; nt++) acc3[nt] = (f32x4){0.f, 0.f, 0.f, 0.f};
#pragma unroll
    for (int ks = 0; ks < 4; ks++) {
      short8 af = *(const short8*)(&h2s[wave][m15 * 136 + ks * 32 + quad * 8]);
#pragma unroll
      for (int nt = 0; nt < 4; nt++) {
        short8 bfr = *(const short8*)&w3l[(ks * 4 + nt) * 512 + lane * 8];
        acc3[nt] = __builtin_amdgcn_mfma_f32_16x16x32_bf16(af, bfr, acc3[nt], 0, 0, 0);
      }
    }
    // ---- ep3: stage, then 8 full 128B rows per store instruction
#pragma unroll
    for (int nt = 0; nt < 4; nt++) {
#pragma unroll
      for (int r = 0; r < 4; r++)
        stg[wave][(quad * 4 + r) * 72 + m15 + 16 * nt] = f2bf(acc3[nt][r] + b3v[nt]);
    }
    {
      int chunk = lane & 7;
#pragma unroll
      for (int it = 0; it < 2; it++) {
        int row_l = (lane >> 3) + it * 8;
        short8 v = *(const short8*)&stg[wave][row_l * 72 + chunk * 8];
        *(short8*)(tok_out + ((size_t)(b0 + row_l) * 8 + d) * 64 + chunk * 8) = v;
      }
    }
  }
}

// ---------------------------------------------------------------- attention (unchanged R6)
__global__ __launch_bounds__(256, 2) void attn_kernel(
    const float* __restrict__ ws, const u16* __restrict__ tok,
    const u16* __restrict__ WA, const u16* __restrict__ WB,
    float* __restrict__ out) {
  __shared__ __align__(16) u16 tokl[2][8 * TOKL_STRIDE];
  __shared__ __align__(16) u16 P[2 * PSIDE];
  const int t = threadIdx.x;
  const int wave = t >> 6, lane = t & 63;
  const int m15 = lane & 15, quad = lane >> 4;
  const int side = wave >> 1, mt = wave & 1;
  const float cst = ws[OFF_CONST];

  const u16* W = side ? WB : WA;
  const float* bias = ws + (side ? OFF_BB : OFF_BA);
  short8 wf0[17], wf1[17];
  float biasv[17];
#pragma unroll
  for (int nt = 0; nt < 17; nt++) {
    const u16* bp = W + (nt * 16 + m15) * 64 + quad * 8;
    wf0[nt] = *(const short8*)bp;
    wf1[nt] = *(const short8*)(bp + 32);
    biasv[nt] = bias[nt * 16 + m15];
  }
  const int e = mt * 4 + (m15 >> 2);
  const int dd = (m15 & 3) + side * 4;
  const int rowc = mt * 16 + quad * 4;
  u16* Pb = &P[side * PSIDE];
  const int elem = t >> 5, sub = t & 31;
  const int tb = sub >> 4, h = (sub >> 2) & 3, q = sub & 3;

  short8 tv0, tv1;
  {
    const short8* g = (const short8*)(tok + (size_t)(blockIdx.x * 16) * 8 * 512);
    tv0 = g[t];
    tv1 = g[t + 256];
  }
  int buf = 0;
  for (int it = 0; it < 16; it++) {
    const int b0el = blockIdx.x * 128 + it * 8;
    {
      int c0 = t, c1 = t + 256;
      *(short8*)&tokl[buf][(c0 >> 6) * TOKL_STRIDE + (c0 & 63) * 8] = tv0;
      *(short8*)&tokl[buf][(c1 >> 6) * TOKL_STRIDE + (c1 & 63) * 8] = tv1;
    }
    if (it + 1 < 16) {
      const short8* g = (const short8*)(tok + (size_t)(b0el + 8) * 512);
      tv0 = g[t];
      tv1 = g[t + 256];
    }
    __syncthreads();
    {
      const u16* abase = &tokl[buf][e * TOKL_STRIDE + dd * 64 + quad * 8];
      short8 a0 = *(const short8*)(abase);
      short8 a1 = *(const short8*)(abase + 32);
#pragma unroll
      for (int nt = 0; nt < 17; nt++) {
        f32x4 acc = {0.f, 0.f, 0.f, 0.f};
        acc = __builtin_amdgcn_mfma_f32_16x16x32_bf16(a0, wf0[nt], acc, 0, 0, 0);
        acc = __builtin_amdgcn_mfma_f32_16x16x32_bf16(a1, wf1[nt], acc, 0, 0, 0);
#pragma unroll
        for (int r = 0; r < 4; r++)
          Pb[(rowc + r) * P_STRIDE + m15 + 16 * nt] = f2bf(acc[r] + biasv[nt]);
      }
    }
    __syncthreads();
    float acc = 0.f;
#pragma unroll
    for (int ti = 0; ti < 2; ti++) {
      const int tag = tb + ti * 2;
      const int qs = tag & 1, cross = tag >> 1;
      const int ks2 = qs ^ cross;
      const u16* Pq = P + qs * PSIDE + (elem * 4 + q) * P_STRIDE + cross * 128 + h * 16;
      float qv[16];
      ld16(Pq, qv);
      const u16* Pk = P + ks2 * PSIDE + (elem * 4) * P_STRIDE + 64 + cross * 128 + h * 16;
      float sc[4];
#pragma unroll
      for (int k = 0; k < 4; k++) {
        float kv[16];
        ld16(Pk + k * P_STRIDE, kv);
        float s = 0.f;
#pragma unroll
        for (int i = 0; i < 16; i++) s += qv[i] * kv[i];
        sc[k] = s;
      }
      float mx = fmaxf(fmaxf(sc[0], sc[1]), fmaxf(sc[2], sc[3]));
      float e0 = __expf(sc[0] - mx), e1 = __expf(sc[1] - mx);
      float e2 = __expf(sc[2] - mx), e3 = __expf(sc[3] - mx);
      const u16* Psv = P + ks2 * PSIDE + (elem * 4) * P_STRIDE + 256 + cross * 4 + h;
      float o = e0 * bf2f(Psv[0]) + e1 * bf2f(Psv[P_STRIDE]) +
                e2 * bf2f(Psv[2 * P_STRIDE]) + e3 * bf2f(Psv[3 * P_STRIDE]);
      acc += o / (e0 + e1 + e2 + e3);
    }
    acc += __shfl_xor(acc, 1);
    acc += __shfl_xor(acc, 2);
    acc += __shfl_xor(acc, 4);
    acc += __shfl_xor(acc, 8);
    acc += __shfl_xor(acc, 16);
    if (sub == 0) {
      float val = 0.125f * acc + cst;
      out[b0el + elem] = val > 0.f ? val : 0.01f * val;
    }
    buf ^= 1;
  }
}

// ---------------------------------------------------------------- launch
extern "C" void kernel_launch(void* const* d_in, const int* in_sizes, int n_in,
                              void* d_out, int out_size, void* d_ws, size_t ws_size,
                              hipStream_t stream) {
  const float* x      = (const float*)d_in[0];
  const float* w1     = (const float*)d_in[1];
  const float* b1     = (const float*)d_in[2];
  const float* w2     = (const float*)d_in[3];
  const float* b2     = (const float*)d_in[4];
  const float* w3     = (const float*)d_in[5];
  const float* b3     = (const float*)d_in[6];
  const float* win_sa = (const float*)d_in[7];
  const float* bin_sa = (const float*)d_in[8];
  const float* wo_sa  = (const float*)d_in[9];
  const float* bo_sa  = (const float*)d_in[10];
  const float* win_sb = (const float*)d_in[11];
  const float* bin_sb = (const float*)d_in[12];
  const float* wo_sb  = (const float*)d_in[13];
  const float* bo_sb  = (const float*)d_in[14];
  const float* win_ca = (const float*)d_in[15];
  const float* bin_ca = (const float*)d_in[16];
  const float* wo_ca  = (const float*)d_in[17];
  const float* bo_ca  = (const float*)d_in[18];
  const float* win_cb = (const float*)d_in[19];
  const float* bin_cb = (const float*)d_in[20];
  const float* wo_cb  = (const float*)d_in[21];
  const float* bo_cb  = (const float*)d_in[22];
  const float* Wf     = (const float*)d_in[23];
  const float* bf     = (const float*)d_in[24];
  float* ws = (float*)d_ws;
  u16* WAp    = (u16*)((char*)d_ws + OFF_WA_B);
  u16* WBp    = (u16*)((char*)d_ws + OFF_WB_B);
  u16* w2p    = (u16*)((char*)d_ws + OFF_W2P_B);
  u16* w3p    = (u16*)((char*)d_ws + OFF_W3P_B);
  u16* tokbuf = (u16*)((char*)d_ws + OFF_TOK_B);
  float* out = (float*)d_out;

  prep_fold<<<4, 64, 0, stream>>>(win_sa, bin_sa, wo_sa, bo_sa,
                                  win_sb, bin_sb, wo_sb, bo_sb,
                                  win_ca, bin_ca, wo_ca, bo_ca,
                                  win_cb, bin_cb, wo_cb, bo_cb,
                                  Wf, ws);
  prep_pack<<<907, 256, 0, stream>>>(w2, w3, win_sa, win_sb, win_ca, win_cb,
                                     bin_sa, bin_sb, bin_ca, bin_cb, bf,
                                     ws, w2p, w3p, WAp, WBp);
  tokens_kernel<<<1024, 256, 0, stream>>>(x, w1, b1, b2, b3, w2p, w3p, tokbuf);
  attn_kernel<<<512, 256, 0, stream>>>(ws, tokbuf, WAp, WBp, out);
}

// Round 8
// 275.584 us; speedup vs baseline: 3.7918x; 1.0169x over previous
//
#include <hip/hip_runtime.h>

typedef unsigned short u16;
typedef __attribute__((ext_vector_type(8))) short short8;
typedef __attribute__((ext_vector_type(4))) float f32x4;

// ws float-index offsets
#define OFF_U     0       // [4][4][64] folded value vectors (tag,h,k)
#define OFF_CV    1024    // [4][4]
#define OFF_CONST 1040
#define OFF_CTAG  1044    // [4] per-tag bo.wfh sums
#define OFF_BA    1056    // [272] fp32 bias for WA cols
#define OFF_BB    1328    // [272]
// ws byte offsets (16B-aligned)
#define OFF_WA_B    6400     // u16 [272][64]
#define OFF_WB_B    41216    // u16 [272][64]
#define OFF_W2P_B   76032    // u16 [8][32][64][8]  w2 in frag order
#define OFF_W3P_B   338176   // u16 [8][16][64][8]  w3 in frag order
#define OFF_TOK_B   469248   // u16 tokens, D-MAJOR: [8][65536][64]

#define P_STRIDE 280
#define PSIDE    (32 * P_STRIDE)

static __device__ __forceinline__ u16 f2bf(float f) {
  unsigned int bits = __float_as_uint(f);
  bits += 0x7fffu + ((bits >> 16) & 1u);
  return (u16)(bits >> 16);
}
static __device__ __forceinline__ float bf2f(u16 u) {
  return __uint_as_float(((unsigned int)u) << 16);
}
static __device__ __forceinline__ void ld16(const u16* p, float* o) {
  short8 v0 = *(const short8*)p;
  short8 v1 = *(const short8*)(p + 8);
#pragma unroll
  for (int i = 0; i < 8; i++) {
    o[i] = bf2f((u16)v0[i]);
    o[8 + i] = bf2f((u16)v1[i]);
  }
}

// ---------------------------------------------------------------- prep 1: fold
__global__ __launch_bounds__(64) void prep_fold(
    const float* __restrict__ win_sa, const float* __restrict__ bin_sa,
    const float* __restrict__ wo_sa,  const float* __restrict__ bo_sa,
    const float* __restrict__ win_sb, const float* __restrict__ bin_sb,
    const float* __restrict__ wo_sb,  const float* __restrict__ bo_sb,
    const float* __restrict__ win_ca, const float* __restrict__ bin_ca,
    const float* __restrict__ wo_ca,  const float* __restrict__ bo_ca,
    const float* __restrict__ win_cb, const float* __restrict__ bin_cb,
    const float* __restrict__ wo_cb,  const float* __restrict__ bo_cb,
    const float* __restrict__ Wf, float* __restrict__ ws) {
  __shared__ float v_lds[64];
  const int t = threadIdx.x;
  const int tag = blockIdx.x;
  const float* wins[4] = {win_sa, win_sb, win_ca, win_cb};
  const float* bins[4] = {bin_sa, bin_sb, bin_ca, bin_cb};
  const float* wos[4]  = {wo_sa, wo_sb, wo_ca, wo_cb};
  const float* bos[4]  = {bo_sa, bo_sb, bo_ca, bo_cb};
  const float* wfh = Wf + ((tag == 0 || tag == 2) ? 0 : 64);
  float v = 0.f;
#pragma unroll
  for (int e = 0; e < 64; e++) v += wos[tag][e * 64 + t] * wfh[e];
  v_lds[t] = v;
  __syncthreads();
#pragma unroll
  for (int h = 0; h < 4; h++) {
    float u = 0.f;
#pragma unroll
    for (int dp = 0; dp < 16; dp++)
      u += wins[tag][(128 + h * 16 + dp) * 64 + t] * v_lds[h * 16 + dp];
    ws[OFF_U + tag * 256 + h * 64 + t] = u;
  }
  if (t < 4) {
    float cv = 0.f;
#pragma unroll
    for (int dp = 0; dp < 16; dp++)
      cv += bins[tag][128 + t * 16 + dp] * v_lds[t * 16 + dp];
    ws[OFF_CV + tag * 4 + t] = cv;
  }
  if (t == 0) {
    float c = 0.f;
#pragma unroll
    for (int e = 0; e < 64; e++) c += bos[tag][e] * wfh[e];
    ws[OFF_CTAG + tag] = c;
  }
}

// ---------------------------------------------------------------- prep 2: pack
__global__ __launch_bounds__(256) void prep_pack(
    const float* __restrict__ w2, const float* __restrict__ w3,
    const float* __restrict__ win_sa, const float* __restrict__ win_sb,
    const float* __restrict__ win_ca, const float* __restrict__ win_cb,
    const float* __restrict__ bin_sa, const float* __restrict__ bin_sb,
    const float* __restrict__ bin_ca, const float* __restrict__ bin_cb,
    const float* __restrict__ bf,
    float* __restrict__ ws, u16* __restrict__ w2p, u16* __restrict__ w3p,
    u16* __restrict__ WA, u16* __restrict__ WB) {
  int idx = blockIdx.x * 256 + threadIdx.x;
  if (idx < 131072) {               // w2p[d][ks*8+nt][lane][j]
    int d = idx >> 14, rem = idx & 16383;
    int f = rem >> 9, ks = f >> 3, nt = f & 7;
    int r2 = rem & 511, l = r2 >> 3, j = r2 & 7;
    int quad = l >> 4, m15 = l & 15;
    w2p[idx] = f2bf(w2[(d * 128 + nt * 16 + m15) * 128 + ks * 32 + quad * 8 + j]);
  } else if (idx < 196608) {        // w3p[d][ks*4+nt][lane][j]
    int i = idx - 131072;
    int d = i >> 13, rem = i & 8191;
    int f = rem >> 9, ks = f >> 2, nt = f & 3;
    int r2 = rem & 511, l = r2 >> 3, j = r2 & 7;
    int quad = l >> 4, m15 = l & 15;
    w3p[i] = f2bf(w3[(d * 64 + nt * 16 + m15) * 128 + ks * 32 + quad * 8 + j]);
  } else if (idx < 214016) {        // WA [272][64]
    int i = idx - 196608, n = i >> 6, k = i & 63;
    float v;
    if (n < 64)       v = win_sa[n * 64 + k] * 0.25f;
    else if (n < 128) v = win_sa[n * 64 + k];
    else if (n < 192) v = win_ca[(n - 128) * 64 + k] * 0.25f;
    else if (n < 256) v = win_cb[(n - 128) * 64 + k];
    else if (n < 260) v = ws[OFF_U + 0 * 256 + (n - 256) * 64 + k];
    else if (n < 264) v = ws[OFF_U + 3 * 256 + (n - 260) * 64 + k];
    else              v = 0.f;
    WA[i] = f2bf(v);
  } else if (idx < 231424) {        // WB [272][64]
    int i = idx - 214016, n = i >> 6, k = i & 63;
    float v;
    if (n < 64)       v = win_sb[n * 64 + k] * 0.25f;
    else if (n < 128) v = win_sb[n * 64 + k];
    else if (n < 192) v = win_cb[(n - 128) * 64 + k] * 0.25f;
    else if (n < 256) v = win_ca[(n - 128) * 64 + k];
    else if (n < 260) v = ws[OFF_U + 1 * 256 + (n - 256) * 64 + k];
    else if (n < 264) v = ws[OFF_U + 2 * 256 + (n - 260) * 64 + k];
    else              v = 0.f;
    WB[i] = f2bf(v);
  } else if (idx < 231696) {        // bA
    int n = idx - 231424;
    float v;
    if (n < 64)       v = bin_sa[n] * 0.25f;
    else if (n < 128) v = bin_sa[n];
    else if (n < 192) v = bin_ca[n - 128] * 0.25f;
    else if (n < 256) v = bin_cb[n - 128];
    else if (n < 260) v = ws[OFF_CV + 0 * 4 + (n - 256)];
    else if (n < 264) v = ws[OFF_CV + 3 * 4 + (n - 260)];
    else              v = 0.f;
    ws[OFF_BA + n] = v;
  } else if (idx < 231968) {        // bB
    int n = idx - 231696;
    float v;
    if (n < 64)       v = bin_sb[n] * 0.25f;
    else if (n < 128) v = bin_sb[n];
    else if (n < 192) v = bin_cb[n - 128] * 0.25f;
    else if (n < 256) v = bin_ca[n - 128];
    else if (n < 260) v = ws[OFF_CV + 1 * 4 + (n - 256)];
    else if (n < 264) v = ws[OFF_CV + 2 * 4 + (n - 260)];
    else              v = 0.f;
    ws[OFF_BB + n] = v;
  } else if (idx == 231968) {
    ws[OFF_CONST] = 0.5f * (ws[OFF_CTAG] + ws[OFF_CTAG + 1] +
                            ws[OFF_CTAG + 2] + ws[OFF_CTAG + 3]) + bf[0];
  }
}

// ---------------------------------------------------------------- tokens (MFMA)
// grid = 1024: d = blockIdx>>7, g = blockIdx&127. Output D-MAJOR: each wave
// stores 2 KB fully-contiguous spans (no 128B-at-1KB-stride RMW traffic).
__global__ __launch_bounds__(256, 2) void tokens_kernel(
    const float* __restrict__ x, const float* __restrict__ w1,
    const float* __restrict__ b1, const float* __restrict__ b2,
    const float* __restrict__ b3, const u16* __restrict__ w2p,
    const u16* __restrict__ w3p, u16* __restrict__ tok_out) {
  __shared__ __align__(16) u16 w2l[16384];
  __shared__ __align__(16) u16 w3l[8192];
  __shared__ __align__(16) u16 h2s[4][16 * 136];
  __shared__ __align__(16) u16 stg[4][16 * 72];
  const int t = threadIdx.x;
  const int wave = t >> 6, lane = t & 63;
  const int m15 = lane & 15, quad = lane >> 4;
  const int d = blockIdx.x >> 7;
  const int g = blockIdx.x & 127;
#pragma unroll
  for (int c = 0; c < 8; c++)
    *(short8*)&w2l[c * 2048 + t * 8] = *(const short8*)&w2p[d * 16384 + c * 2048 + t * 8];
#pragma unroll
  for (int c = 0; c < 4; c++)
    *(short8*)&w3l[c * 2048 + t * 8] = *(const short8*)&w3p[d * 8192 + c * 2048 + t * 8];
  __syncthreads();
  short8 w2f[4][8];
#pragma unroll
  for (int ks = 0; ks < 4; ks++)
#pragma unroll
    for (int nt = 0; nt < 8; nt++)
      w2f[ks][nt] = *(const short8*)&w2l[(ks * 8 + nt) * 512 + lane * 8];
  float b2v[8], b3v[4];
#pragma unroll
  for (int nt = 0; nt < 8; nt++) b2v[nt] = b2[d * 128 + m15 + 16 * nt];
#pragma unroll
  for (int nt = 0; nt < 4; nt++) b3v[nt] = b3[d * 64 + m15 + 16 * nt];

  for (int i = 0; i < 8; i++) {
    const int b0 = g * 512 + wave * 128 + i * 16;
    const float xv = x[(size_t)(b0 + m15) * 8 + d];
    short8 afr[4];
#pragma unroll
    for (int ks = 0; ks < 4; ks++) {
      const float* w1p = w1 + d * 128 + ks * 32 + quad * 8;
      const float* b1p = b1 + d * 128 + ks * 32 + quad * 8;
      float4 wa = *(const float4*)w1p, wb = *(const float4*)(w1p + 4);
      float4 ba = *(const float4*)b1p, bb = *(const float4*)(b1p + 4);
      short8 a;
      a[0] = (short)f2bf(__sinf(xv * wa.x + ba.x));
      a[1] = (short)f2bf(__sinf(xv * wa.y + ba.y));
      a[2] = (short)f2bf(__sinf(xv * wa.z + ba.z));
      a[3] = (short)f2bf(__sinf(xv * wa.w + ba.w));
      a[4] = (short)f2bf(__sinf(xv * wb.x + bb.x));
      a[5] = (short)f2bf(__sinf(xv * wb.y + bb.y));
      a[6] = (short)f2bf(__sinf(xv * wb.z + bb.z));
      a[7] = (short)f2bf(__sinf(xv * wb.w + bb.w));
      afr[ks] = a;
    }
    f32x4 acc2[8];
#pragma unroll
    for (int nt = 0; nt < 8; nt++) acc2[nt] = (f32x4){0.f, 0.f, 0.f, 0.f};
#pragma unroll
    for (int ks = 0; ks < 4; ks++)
#pragma unroll
      for (int nt = 0; nt < 8; nt++)
        acc2[nt] = __builtin_amdgcn_mfma_f32_16x16x32_bf16(afr[ks], w2f[ks][nt],
                                                           acc2[nt], 0, 0, 0);
#pragma unroll
    for (int nt = 0; nt < 8; nt++) {
#pragma unroll
      for (int r = 0; r < 4; r++)
        h2s[wave][(quad * 4 + r) * 136 + m15 + 16 * nt] =
            f2bf(__sinf(acc2[nt][r] + b2v[nt]));
    }
    f32x4 acc3[4];
#pragma unroll
    for (int nt = 0; nt < 4; nt++) acc3[nt] = (f32x4){0.f, 0.f, 0.f, 0.f};
#pragma unroll
    for (int ks = 0; ks < 4; ks++) {
      short8 af = *(const short8*)(&h2s[wave][m15 * 136 + ks * 32 + quad * 8]);
#pragma unroll
      for (int nt = 0; nt < 4; nt++) {
        short8 bfr = *(const short8*)&w3l[(ks * 4 + nt) * 512 + lane * 8];
        acc3[nt] = __builtin_amdgcn_mfma_f32_16x16x32_bf16(af, bfr, acc3[nt], 0, 0, 0);
      }
    }
#pragma unroll
    for (int nt = 0; nt < 4; nt++) {
#pragma unroll
      for (int r = 0; r < 4; r++)
        stg[wave][(quad * 4 + r) * 72 + m15 + 16 * nt] = f2bf(acc3[nt][r] + b3v[nt]);
    }
    {
      int chunk = lane & 7;
#pragma unroll
      for (int it = 0; it < 2; it++) {
        int row_l = (lane >> 3) + it * 8;
        short8 v = *(const short8*)&stg[wave][row_l * 72 + chunk * 8];
        // D-MAJOR: contiguous 1KB per 64-lane store phase
        *(short8*)(tok_out + ((size_t)(d * 65536 + b0 + row_l)) * 64 + chunk * 8) = v;
      }
    }
  }
}

// ---------------------------------------------------------------- attention
// A-frags straight from global (d-major tokens) -> no tokl stage. P double-
// buffered -> ONE barrier per iteration; next-iter A-frags prefetched to regs.
__global__ __launch_bounds__(256, 2) void attn_kernel(
    const float* __restrict__ ws, const u16* __restrict__ tok,
    const u16* __restrict__ WA, const u16* __restrict__ WB,
    float* __restrict__ out) {
  __shared__ __align__(16) u16 P[2][2 * PSIDE];
  const int t = threadIdx.x;
  const int wave = t >> 6, lane = t & 63;
  const int m15 = lane & 15, quad = lane >> 4;
  const int side = wave >> 1, mt = wave & 1;
  const float cst = ws[OFF_CONST];

  const u16* W = side ? WB : WA;
  const float* bias = ws + (side ? OFF_BB : OFF_BA);
  short8 wf0[17], wf1[17];
  float biasv[17];
#pragma unroll
  for (int nt = 0; nt < 17; nt++) {
    const u16* bp = W + (nt * 16 + m15) * 64 + quad * 8;
    wf0[nt] = *(const short8*)bp;
    wf1[nt] = *(const short8*)(bp + 32);
    biasv[nt] = bias[nt * 16 + m15];
  }
  const int e = mt * 4 + (m15 >> 2);
  const int dd = (m15 & 3) + side * 4;
  const int rowc = mt * 16 + quad * 4;
  const int elem = t >> 5, sub = t & 31;
  const int tb = sub >> 4, h = (sub >> 2) & 3, q = sub & 3;

  // iter-0 A-frags from global: row = tok_d[dd][b0el + e], cols quad*8(+32)
  const u16* abase = tok + ((size_t)(dd * 65536 + blockIdx.x * 128 + e)) * 64 + quad * 8;
  short8 a0 = *(const short8*)abase;
  short8 a1 = *(const short8*)(abase + 32);
  int pb = 0;
  for (int it = 0; it < 16; it++) {
    const int b0el = blockIdx.x * 128 + it * 8;
    // prefetch next iteration's A-frags (hidden under stage A+B)
    short8 a0n = a0, a1n = a1;
    if (it + 1 < 16) {
      const u16* nb = abase + (size_t)(it + 1) * 512;
      a0n = *(const short8*)nb;
      a1n = *(const short8*)(nb + 32);
    }
    // ---- stage A: P[pb] = tok @ W (+bias)
    {
      u16* Pb = &P[pb][side * PSIDE];
#pragma unroll
      for (int nt = 0; nt < 17; nt++) {
        f32x4 acc = {0.f, 0.f, 0.f, 0.f};
        acc = __builtin_amdgcn_mfma_f32_16x16x32_bf16(a0, wf0[nt], acc, 0, 0, 0);
        acc = __builtin_amdgcn_mfma_f32_16x16x32_bf16(a1, wf1[nt], acc, 0, 0, 0);
#pragma unroll
        for (int r = 0; r < 4; r++)
          Pb[(rowc + r) * P_STRIDE + m15 + 16 * nt] = f2bf(acc[r] + biasv[nt]);
      }
    }
    __syncthreads();
    // ---- stage B reads P[pb]; next stage A writes P[pb^1] -> no 2nd barrier
    const u16* Pc = &P[pb][0];
    float acc = 0.f;
#pragma unroll
    for (int ti = 0; ti < 2; ti++) {
      const int tag = tb + ti * 2;
      const int qs = tag & 1, cross = tag >> 1;
      const int ks2 = qs ^ cross;
      const u16* Pq = Pc + qs * PSIDE + (elem * 4 + q) * P_STRIDE + cross * 128 + h * 16;
      float qv[16];
      ld16(Pq, qv);
      const u16* Pk = Pc + ks2 * PSIDE + (elem * 4) * P_STRIDE + 64 + cross * 128 + h * 16;
      float sc[4];
#pragma unroll
      for (int k = 0; k < 4; k++) {
        float kv[16];
        ld16(Pk + k * P_STRIDE, kv);
        float s = 0.f;
#pragma unroll
        for (int i = 0; i < 16; i++) s += qv[i] * kv[i];
        sc[k] = s;
      }
      float mx = fmaxf(fmaxf(sc[0], sc[1]), fmaxf(sc[2], sc[3]));
      float e0 = __expf(sc[0] - mx), e1 = __expf(sc[1] - mx);
      float e2 = __expf(sc[2] - mx), e3 = __expf(sc[3] - mx);
      const u16* Psv = Pc + ks2 * PSIDE + (elem * 4) * P_STRIDE + 256 + cross * 4 + h;
      float o = e0 * bf2f(Psv[0]) + e1 * bf2f(Psv[P_STRIDE]) +
                e2 * bf2f(Psv[2 * P_STRIDE]) + e3 * bf2f(Psv[3 * P_STRIDE]);
      acc += o / (e0 + e1 + e2 + e3);
    }
    acc += __shfl_xor(acc, 1);
    acc += __shfl_xor(acc, 2);
    acc += __shfl_xor(acc, 4);
    acc += __shfl_xor(acc, 8);
    acc += __shfl_xor(acc, 16);
    if (sub == 0) {
      float val = 0.125f * acc + cst;
      out[b0el + elem] = val > 0.f ? val : 0.01f * val;
    }
    a0 = a0n;
    a1 = a1n;
    pb ^= 1;
  }
}

// ---------------------------------------------------------------- launch
extern "C" void kernel_launch(void* const* d_in, const int* in_sizes, int n_in,
                              void* d_out, int out_size, void* d_ws, size_t ws_size,
                              hipStream_t stream) {
  const float* x      = (const float*)d_in[0];
  const float* w1     = (const float*)d_in[1];
  const float* b1     = (const float*)d_in[2];
  const float* w2     = (const float*)d_in[3];
  const float* b2     = (const float*)d_in[4];
  const float* w3     = (const float*)d_in[5];
  const float* b3     = (const float*)d_in[6];
  const float* win_sa = (const float*)d_in[7];
  const float* bin_sa = (const float*)d_in[8];
  const float* wo_sa  = (const float*)d_in[9];
  const float* bo_sa  = (const float*)d_in[10];
  const float* win_sb = (const float*)d_in[11];
  const float* bin_sb = (const float*)d_in[12];
  const float* wo_sb  = (const float*)d_in[13];
  const float* bo_sb  = (const float*)d_in[14];
  const float* win_ca = (const float*)d_in[15];
  const float* bin_ca = (const float*)d_in[16];
  const float* wo_ca  = (const float*)d_in[17];
  const float* bo_ca  = (const float*)d_in[18];
  const float* win_cb = (const float*)d_in[19];
  const float* bin_cb = (const float*)d_in[20];
  const float* wo_cb  = (const float*)d_in[21];
  const float* bo_cb  = (const float*)d_in[22];
  const float* Wf     = (const float*)d_in[23];
  const float* bf     = (const float*)d_in[24];
  float* ws = (float*)d_ws;
  u16* WAp    = (u16*)((char*)d_ws + OFF_WA_B);
  u16* WBp    = (u16*)((char*)d_ws + OFF_WB_B);
  u16* w2p    = (u16*)((char*)d_ws + OFF_W2P_B);
  u16* w3p    = (u16*)((char*)d_ws + OFF_W3P_B);
  u16* tokbuf = (u16*)((char*)d_ws + OFF_TOK_B);
  float* out = (float*)d_out;

  prep_fold<<<4, 64, 0, stream>>>(win_sa, bin_sa, wo_sa, bo_sa,
                                  win_sb, bin_sb, wo_sb, bo_sb,
                                  win_ca, bin_ca, wo_ca, bo_ca,
                                  win_cb, bin_cb, wo_cb, bo_cb,
                                  Wf, ws);
  prep_pack<<<907, 256, 0, stream>>>(w2, w3, win_sa, win_sb, win_ca, win_cb,
                                     bin_sa, bin_sb, bin_ca, bin_cb, bf,
                                     ws, w2p, w3p, WAp, WBp);
  tokens_kernel<<<1024, 256, 0, stream>>>(x, w1, b1, b2, b3, w2p, w3p, tokbuf);
  attn_kernel<<<512, 256, 0, stream>>>(ws, tokbuf, WAp, WBp, out);
}